// Round 17
// baseline (158.202 us; speedup 1.0000x reference)
//
#include <hip/hip_runtime.h>
#include <hip/hip_bf16.h>

// Problem constants
constexpr int BB  = 2;
constexpr int CHN = 256;
constexpr int HH  = 80;
constexpr int WW  = 80;
constexpr int EE  = 64;
constexpr int HO  = 160;
constexpr int WO  = 160;

// Workspace layout (float offsets)
constexpr int OFF_WT_EN = 0;                    // BF bf16 B-fragments (16384 ushort = 8192 floats)
constexpr int OFF_WT_DE = 16384;                // [256][64]  w1_de transposed
constexpr int OFF_WC    = 32768;                // [64][3][3][25] conv2_k transposed
constexpr int OFF_CES   = 47168;                // [B][4][162][162][16] padded+scrambled ce
constexpr int CES_SZ    = 2 * 4 * 162 * 162 * 16;   // 3,359,232
constexpr int OFF_CDG   = OFF_CES + CES_SZ;     // [B][82][82][64] padded cd
constexpr int CDG_SZ    = 2 * 82 * 82 * 64;     // 860,672
constexpr int OFF_GATE  = OFF_CDG + CDG_SZ;     // [B][80][80]
constexpr int OFF_KERN  = OFF_GATE + 2 * 80 * 80;   // [B][80][80][25][4] softmaxed (o-major, q-minor!)

constexpr int NPB = BB * 82 * 82;     // 13448

using bf16x8 = __attribute__((ext_vector_type(8))) short;
using f32x4  = __attribute__((ext_vector_type(4))) float;

// X-macro: apply F to 0..24 (forces compile-time indices -> registers; rule #20)
#define REP25(F) F(0) F(1) F(2) F(3) F(4) F(5) F(6) F(7) F(8) F(9) F(10) F(11) \
                 F(12) F(13) F(14) F(15) F(16) F(17) F(18) F(19) F(20) F(21) F(22) F(23) F(24)

// ---------------------------------------------------------------------------
// Prep: wt_de transpose (conv1b), WC transpose (kern), and BF = bf16 MFMA
// B-fragments of w1_en for conv1a.
// ---------------------------------------------------------------------------
__global__ __launch_bounds__(256) void fade_prep(
    const float* __restrict__ w1_en, const float* __restrict__ w1_de,
    const float* __restrict__ conv2_k, float* __restrict__ ws) {
  int idx = blockIdx.x * 256 + threadIdx.x;
  if (idx < 16384) {
    int c = idx >> 6, e = idx & 63;           // dest = [c][e]
    ws[OFF_WT_DE + idx] = w1_de[e * CHN + c];
    // BF fragment (reuses old wt_en slot, as ushort)
    int j = idx & 7, l = (idx >> 3) & 63, et = (idx >> 9) & 3, ks = idx >> 11;
    int cc = ks * 32 + (l >> 4) * 8 + j;
    int ee = et * 16 + (l & 15);
    unsigned u = __float_as_uint(w1_en[ee * CHN + cc]);
    u = (u + 0x7FFFu + ((u >> 16) & 1u)) >> 16;   // RNE to bf16
    ((unsigned short*)(ws + OFF_WT_EN))[idx] = (unsigned short)u;
  }
  if (idx < 14400) {
    // dest idx = (e*9 + t)*25 + o ; src = conv2_k[(o*64 + e)*9 + t]
    int e = idx / 225, rem = idx % 225, t = rem / 25, o = rem % 25;
    ws[OFF_WC + idx] = conv2_k[(o * EE + e) * 9 + t];
  }
}

// ---------------------------------------------------------------------------
// border: zero-fill the pad border of ce_s (yy=0,161; xx=0,161).
// ---------------------------------------------------------------------------
__global__ __launch_bounds__(256) void fade_border(float* __restrict__ ces) {
  int idx = blockIdx.x * 256 + threadIdx.x;
  if (idx >= 82432) return;
  int e4 = idx & 3;
  int rest = idx >> 2;
  int posb = rest % 644;
  int rest2 = rest / 644;
  int q = rest2 & 3, b = rest2 >> 2;
  int yy, xx;
  if (posb < 162)      { yy = 0;   xx = posb; }
  else if (posb < 324) { yy = 161; xx = posb - 162; }
  else if (posb < 484) { xx = 0;   yy = posb - 324 + 1; }
  else                 { xx = 161; yy = posb - 484 + 1; }
  float4 z = make_float4(0.f, 0.f, 0.f, 0.f);
  *(float4*)(ces + ((((size_t)b * 4 + q) * 162 + yy) * 162 + xx) * 16 + e4 * 4) = z;
}

// ---------------------------------------------------------------------------
// conv1a: ce = 1x1(en) via bf16 MFMA (r14: measured win, total -23us).
// ---------------------------------------------------------------------------
__global__ __launch_bounds__(256) void fade_conv1a(
    const float* __restrict__ en, const float* __restrict__ b1_en,
    const unsigned short* __restrict__ BFu, float* __restrict__ ces) {
  __shared__ float buf[32][65];
  int bi = blockIdx.x;
  int b = bi / 400;
  int pos0 = (bi % 400) * 64;       // within batch plane (25600)
  int tid = threadIdx.x;
  int lane = tid & 63;
  int w = __builtin_amdgcn_readfirstlane(tid >> 6);   // 0..3
  int l15 = lane & 15, lg = lane >> 4;

  const float* ep = en + (size_t)b * CHN * 25600 + pos0;
  const bf16x8* BFF = (const bf16x8*)BFu;

  f32x4 acc0, acc1, acc2, acc3;
  { float bv = b1_en[l15];      acc0 = (f32x4){bv, bv, bv, bv}; }
  { float bv = b1_en[16 + l15]; acc1 = (f32x4){bv, bv, bv, bv}; }
  { float bv = b1_en[32 + l15]; acc2 = (f32x4){bv, bv, bv, bv}; }
  { float bv = b1_en[48 + l15]; acc3 = (f32x4){bv, bv, bv, bv}; }

  int cg = tid >> 6, po = tid & 63;
  for (int ks = 0; ks < 8; ++ks) {
    __syncthreads();
#pragma unroll
    for (int i = 0; i < 8; ++i) {
      int c = i * 4 + cg;
      buf[c][po] = ep[(size_t)(ks * 32 + c) * 25600 + po];
    }
    __syncthreads();
    bf16x8 av;
#define LDA_(j) { unsigned u = __float_as_uint(buf[lg * 8 + (j)][w * 16 + l15]); \
    u = (u + 0x7FFFu + ((u >> 16) & 1u)) >> 16; av[(j)] = (short)u; }
    LDA_(0) LDA_(1) LDA_(2) LDA_(3) LDA_(4) LDA_(5) LDA_(6) LDA_(7)
#undef LDA_
    const bf16x8* bp = BFF + ks * 256 + lane;
    bf16x8 b0 = bp[0], b1 = bp[64], b2 = bp[128], b3 = bp[192];
    acc0 = __builtin_amdgcn_mfma_f32_16x16x32_bf16(av, b0, acc0, 0, 0, 0);
    acc1 = __builtin_amdgcn_mfma_f32_16x16x32_bf16(av, b1, acc1, 0, 0, 0);
    acc2 = __builtin_amdgcn_mfma_f32_16x16x32_bf16(av, b2, acc2, 0, 0, 0);
    acc3 = __builtin_amdgcn_mfma_f32_16x16x32_bf16(av, b3, acc3, 0, 0, 0);
  }

  // scrambled write: ce_s[b][q][yy][xx][e'] = acc_full[4e'+q]; e = 4e'+q
  constexpr size_t QSTR = (size_t)162 * 162 * 16;
  float* cb = ces + (size_t)b * 4 * QSTR;
  int pbase = pos0 + w * 16 + lg * 4;
  int q = l15 & 3;
#define WR_(r) { int p = pbase + (r); int y = p / 160, x = p - y * 160; \
    size_t sb = (size_t)q * QSTR + (size_t)((y + 1) * 162 + (x + 1)) * 16 + (l15 >> 2); \
    cb[sb +  0] = acc0[(r)]; \
    cb[sb +  4] = acc1[(r)]; \
    cb[sb +  8] = acc2[(r)]; \
    cb[sb + 12] = acc3[(r)]; }
  WR_(0) WR_(1) WR_(2) WR_(3)
#undef WR_
}

// ---------------------------------------------------------------------------
// conv1b: cd = 1x1(de) -> padded cdg, + gate. Exact r7 part-B shape.
// ---------------------------------------------------------------------------
__global__ __launch_bounds__(256) void fade_conv1b(
    const float* __restrict__ de,
    const float* __restrict__ gate_w, const float* __restrict__ gate_b,
    const float* __restrict__ wt_de,
    float* __restrict__ cdg, float* __restrict__ gateo) {
  int tid = threadIdx.x;
  int id64 = tid & 63;
  int eg = __builtin_amdgcn_readfirstlane(tid >> 6);   // 0..3
  int pos = blockIdx.x * 64 + id64;
  if (pos >= NPB) return;

  int b = pos / (82 * 82), r = pos % (82 * 82);
  int yy = r / 82, xx = r % 82;
  int y = yy - 1, x = xx - 1;
  float* cop = cdg + (((size_t)b * 82 + yy) * 82 + xx) * 64 + eg * 16;
  if (y >= 0 && y < HH && x >= 0 && x < WW) {
    float acc[16];
#pragma unroll
    for (int e = 0; e < 16; ++e) acc[e] = 0.f;
    float g = gate_b[0];
    const float* dp = de + (size_t)b * CHN * HH * WW + (size_t)y * WW + x;
    float cur[8];
#pragma unroll
    for (int j = 0; j < 8; ++j) cur[j] = dp[(size_t)j * HH * WW];
    for (int c0 = 0; c0 < CHN; c0 += 8) {
      float nxt[8];
      if (c0 + 8 < CHN) {
#pragma unroll
        for (int j = 0; j < 8; ++j) nxt[j] = dp[(size_t)(c0 + 8 + j) * HH * WW];
      }
#pragma unroll
      for (int j = 0; j < 8; ++j) {
        float v = cur[j];
        const float* wr = wt_de + (c0 + j) * 64 + eg * 16;
#pragma unroll
        for (int e = 0; e < 16; ++e) acc[e] = fmaf(v, wr[e], acc[e]);
        g = fmaf(v, gate_w[c0 + j], g);
      }
      if (c0 + 8 < CHN) {
#pragma unroll
        for (int j = 0; j < 8; ++j) cur[j] = nxt[j];
      }
    }
#pragma unroll
    for (int m = 0; m < 4; ++m) {
      float4 v = make_float4(acc[4 * m], acc[4 * m + 1], acc[4 * m + 2], acc[4 * m + 3]);
      *(float4*)(cop + m * 4) = v;
    }
    if (eg == 0)
      gateo[((size_t)b * 80 + y) * 80 + x] = 1.f / (1.f + __expf(-g));
  } else {
    float4 z = make_float4(0.f, 0.f, 0.f, 0.f);
#pragma unroll
    for (int m = 0; m < 4; ++m) *(float4*)(cop + m * 4) = z;
  }
}

// ---------------------------------------------------------------------------
// kern: MERGED k_de+k_en tap loop (r13 win). Runtime d-loop (r8 lesson);
// two-phase LDS reduction (32KB).
// ---------------------------------------------------------------------------
__global__ __launch_bounds__(512) void fade_kern(
    const float* __restrict__ WC, const float* __restrict__ CES,
    const float* __restrict__ CDG, const float* __restrict__ conv2_b,
    float* __restrict__ KERN) {
  __shared__ float part[64 * 101];   // [row][(wv&3)*25+o], stride 101 (conflict-free)
  __shared__ float score[64 * 27];
  int bi = blockIdx.x;
  int b = bi / 400, t = bi % 400;
  int th0 = (t / 20) * 4, tw0 = (t % 20) * 4;
  int tid = threadIdx.x;
  int lane = tid & 63;
  int wv = __builtin_amdgcn_readfirstlane(tid >> 6);   // 0..7 K-slice
  int cell = lane >> 2, q = lane & 3;
  int h = th0 + (cell >> 2), w = tw0 + (cell & 3);

#define KDECL_(i) float a##i = 0.f;
  REP25(KDECL_)

#define KCH(val, base) { const float vv = (val); const float* wb = (base); \
    REP25(KFMA_) }
#define KFMA_(i) a##i = fmaf(vv, wb[(i)], a##i);

  // merged k_de + k_en over 9 taps; channels 8wv..8wv+8
  {
    int g = wv >> 1;
    const int pt = (g < 2) ? 1 : 0;
    const int pl = (g & 1) ? 0 : 1;
    const int eb = 8 * (wv & 1);
    for (int d = 0; d < 9; ++d) {
      int di = d / 3, dj = d - 3 * di;
      const float* cpd = CDG + (((size_t)b * 82 + (h + di)) * 82 + (w + dj)) * 64 + 8 * wv;
      float4 u0 = *(const float4*)(cpd);
      float4 u1 = *(const float4*)(cpd + 4);
      int yy = 2 * h + di - pt + 1;
      int xx = 2 * w + dj - pl + 1;
      const float* cpe = CES + ((((size_t)b * 4 + q) * 162 + yy) * 162 + xx) * 16 + eb;
      float4 v0 = *(const float4*)(cpe);
      float4 v1 = *(const float4*)(cpe + 4);
      const float* wt = WC + (8 * wv * 9 + d) * 25;
      KCH(u0.x + v0.x, wt)         KCH(u0.y + v0.y, wt + 225)
      KCH(u0.z + v0.z, wt + 450)   KCH(u0.w + v0.w, wt + 675)
      KCH(u1.x + v1.x, wt + 900)   KCH(u1.y + v1.y, wt + 1125)
      KCH(u1.z + v1.z, wt + 1350)  KCH(u1.w + v1.w, wt + 1575)
    }
  }

  {
    int pbase = lane * 101 + (wv & 3) * 25;
    if (wv < 4) {
#define KST_(i) part[pbase + (i)] = a##i;
      REP25(KST_)
    }
    __syncthreads();
    if (wv >= 4) {
#define KAD_(i) part[pbase + (i)] += a##i;
      REP25(KAD_)
    }
  }
  __syncthreads();

  {
    int row = tid & 63, sub = tid >> 6;
    int nO = (sub == 7) ? 4 : 3;
    for (int m = 0; m < nO; ++m) {
      int o = sub * 3 + m;
      float s = 0.f;
#pragma unroll
      for (int w4 = 0; w4 < 4; ++w4) s += part[row * 101 + w4 * 25 + o];
      score[row * 27 + o] = s + 2.f * conv2_b[o];   // bias in BOTH k_en and k_de
    }
  }
  __syncthreads();

  if (tid < 64) {
    int sbase = tid * 27;
#define SLD_(i) float s##i = score[sbase + (i)];
    REP25(SLD_)
    float mx = s0;
#define SMX_(i) mx = fmaxf(mx, s##i);
    REP25(SMX_)
    float sum = 0.f;
#define SEX_(i) s##i = __expf(s##i - mx); sum += s##i;
    REP25(SEX_)
    float inv = 1.f / sum;
    int cl = tid >> 2, qq = tid & 3;
    int hh = th0 + (cl >> 2), ww2 = tw0 + (cl & 3);
    float* kp = KERN + (size_t)(b * 6400 + hh * 80 + ww2) * 100;
#define SWR_(i) kp[(i) * 4 + qq] = s##i * inv;
    REP25(SWR_)
  }
}

// ---------------------------------------------------------------------------
// final: CARAFE + gate blend. r15 structure (thread = site x s1-half x
// channel-group wave, kern = 25 named float2 pre-scaled by 1-gate), PLUS
// the fix r15 was missing: VGPR=44 proved the compiler STILL remats the
// kern loads into the channel loop (load+mul chains are rematerializable).
// asm volatile pins make each k##o OPAQUE -> must stay in a VGPR.
// Live-set ~90 < the (256,4) 128-VGPR cap -> no spill, 4 blocks/CU.
// ---------------------------------------------------------------------------
__global__ __launch_bounds__(256, 4) void fade_final(
    const float* __restrict__ en, const float* __restrict__ de,
    const float* __restrict__ KERN, const float* __restrict__ GATE,
    float* __restrict__ out) {
  __shared__ float sde[32 * 105];   // 32 channels x (8 rows x 13 cols pad)
  int bi = blockIdx.x;
  int b = bi / 1600, r = bi % 1600;
  int t = r >> 3, cc = r & 7;
  int th0 = (t / 10) * 4, tw0 = (t % 10) * 8;
  int tid = threadIdx.x;
  int cell = tid & 31;               // site in 4x8 tile
  int s1 = (tid >> 5) & 1;           // output row-half (sub-pixel row)
  int cg = tid >> 6;                 // wave index = channel group (uniform)
  int chh = cell >> 3, cw = cell & 7;
  int h = th0 + chh, w = tw0 + cw;

  // stage de: channels cc*32 .. +32, rows th0-2..+5, cols tw0-2..+9
  for (int kk = tid; kk < 3072; kk += 256) {
    int ci = kk / 96, rem = kk % 96, rr = rem / 12, c2 = rem % 12;
    int dr = th0 - 2 + rr, dc = tw0 - 2 + c2;
    float v = 0.f;
    if (dr >= 0 && dr < HH && dc >= 0 && dc < WW)
      v = de[((size_t)(b * CHN + cc * 32 + ci) * HH + dr) * WW + dc];
    sde[ci * 105 + rr * 13 + c2] = v;
  }
  __syncthreads();

  float gv = GATE[((size_t)b * 80 + h) * 80 + w];
  float gv1 = 1.f - gv;

  // kern float2 for this (site, s1), pre-scaled by (1-gate), PINNED in
  // registers via opaque asm (cannot be rematerialized or re-loaded).
  const float2* kp2 = (const float2*)(KERN + (size_t)(b * 6400 + h * 80 + w) * 100);
#define FKD_(o) float2 k##o = kp2[(o) * 2 + s1]; k##o.x *= gv1; k##o.y *= gv1; \
    asm volatile("" : "+v"(k##o.x), "+v"(k##o.y));
  REP25(FKD_)

  for (int i = 0; i < 8; ++i) {
    int cl = cg * 8 + i;             // wave-uniform channel within chunk
    int sbase2 = cl * 105 + chh * 13 + cw;
#define FWD_(o) float w##o = sde[sbase2 + ((o) / 5) * 13 + ((o) % 5)];
    REP25(FWD_)
    float sA = 0.f, sB = 0.f;        // s2 = 0, 1
#define FCF_(o) sA = fmaf(w##o, k##o.x, sA); sB = fmaf(w##o, k##o.y, sB);
    REP25(FCF_)

    int c = cc * 32 + cl;
    const float* ep = en + ((size_t)(b * CHN + c) * HO + 2 * h + s1) * WO + 2 * w;
    float* op = out + ((size_t)(b * CHN + c) * HO + 2 * h + s1) * WO + 2 * w;
    float2 e = *(const float2*)ep;
    float2 rr;
    rr.x = fmaf(gv, e.x, sA);
    rr.y = fmaf(gv, e.y, sB);
    *(float2*)op = rr;
  }
}

// ---------------------------------------------------------------------------
extern "C" void kernel_launch(void* const* d_in, const int* in_sizes, int n_in,
                              void* d_out, int out_size, void* d_ws, size_t ws_size,
                              hipStream_t stream) {
  const float* en      = (const float*)d_in[0];
  const float* de      = (const float*)d_in[1];
  const float* gate_w  = (const float*)d_in[2];
  const float* gate_b  = (const float*)d_in[3];
  const float* w1_en   = (const float*)d_in[4];
  const float* b1_en   = (const float*)d_in[5];
  const float* w1_de   = (const float*)d_in[6];
  const float* conv2_k = (const float*)d_in[7];
  const float* conv2_b = (const float*)d_in[8];
  float* ws  = (float*)d_ws;
  float* out = (float*)d_out;

  const unsigned short* bfu = (const unsigned short*)(ws + OFF_WT_EN);
  float* wt_de = ws + OFF_WT_DE;
  float* wc    = ws + OFF_WC;
  float* cesb  = ws + OFF_CES;
  float* cdgb  = ws + OFF_CDG;
  float* gateo = ws + OFF_GATE;
  float* kernb = ws + OFF_KERN;

  hipLaunchKernelGGL(fade_prep,   dim3(64),   dim3(256), 0, stream, w1_en, w1_de, conv2_k, ws);
  hipLaunchKernelGGL(fade_border, dim3(322),  dim3(256), 0, stream, cesb);
  hipLaunchKernelGGL(fade_conv1a, dim3(800),  dim3(256), 0, stream, en, b1_en, bfu, cesb);
  hipLaunchKernelGGL(fade_conv1b, dim3(211),  dim3(256), 0, stream,
                     de, gate_w, gate_b, wt_de, cdgb, gateo);
  hipLaunchKernelGGL(fade_kern,   dim3(800),  dim3(512), 0, stream,
                     wc, cesb, cdgb, conv2_b, kernb);
  hipLaunchKernelGGL(fade_final,  dim3(3200), dim3(256), 0, stream,
                     en, de, kernb, gateo, out);
}

// Round 18
// 132.909 us; speedup vs baseline: 1.1903x; 1.1903x over previous
//
#include <hip/hip_runtime.h>
#include <hip/hip_bf16.h>

// Problem constants
constexpr int BB  = 2;
constexpr int CHN = 256;
constexpr int HH  = 80;
constexpr int WW  = 80;
constexpr int EE  = 64;
constexpr int HO  = 160;
constexpr int WO  = 160;

// Workspace layout (float offsets)
constexpr int OFF_WT_EN = 0;                    // BF bf16 B-fragments (16384 ushort = 8192 floats)
constexpr int OFF_WT_DE = 16384;                // [256][64]  w1_de transposed
constexpr int OFF_WC    = 32768;                // [64][3][3][25] conv2_k transposed
constexpr int OFF_CES   = 47168;                // [B][4][162][162][16] padded+scrambled ce
constexpr int CES_SZ    = 2 * 4 * 162 * 162 * 16;   // 3,359,232
constexpr int OFF_CDG   = OFF_CES + CES_SZ;     // [B][82][82][64] padded cd
constexpr int CDG_SZ    = 2 * 82 * 82 * 64;     // 860,672
constexpr int OFF_GATE  = OFF_CDG + CDG_SZ;     // [B][80][80]
constexpr int OFF_KERN  = OFF_GATE + 2 * 80 * 80;   // [B][80][80][25][4] softmaxed (o-major, q-minor!)

constexpr int NPB = BB * 82 * 82;     // 13448

using bf16x8 = __attribute__((ext_vector_type(8))) short;
using f32x4  = __attribute__((ext_vector_type(4))) float;

// X-macro: apply F to 0..24 (forces compile-time indices -> registers; rule #20)
#define REP25(F) F(0) F(1) F(2) F(3) F(4) F(5) F(6) F(7) F(8) F(9) F(10) F(11) \
                 F(12) F(13) F(14) F(15) F(16) F(17) F(18) F(19) F(20) F(21) F(22) F(23) F(24)

// ---------------------------------------------------------------------------
// Prep: wt_de transpose (conv1b), WC transpose (kern), and BF = bf16 MFMA
// B-fragments of w1_en for conv1a.
// ---------------------------------------------------------------------------
__global__ __launch_bounds__(256) void fade_prep(
    const float* __restrict__ w1_en, const float* __restrict__ w1_de,
    const float* __restrict__ conv2_k, float* __restrict__ ws) {
  int idx = blockIdx.x * 256 + threadIdx.x;
  if (idx < 16384) {
    int c = idx >> 6, e = idx & 63;           // dest = [c][e]
    ws[OFF_WT_DE + idx] = w1_de[e * CHN + c];
    // BF fragment (reuses old wt_en slot, as ushort)
    int j = idx & 7, l = (idx >> 3) & 63, et = (idx >> 9) & 3, ks = idx >> 11;
    int cc = ks * 32 + (l >> 4) * 8 + j;
    int ee = et * 16 + (l & 15);
    unsigned u = __float_as_uint(w1_en[ee * CHN + cc]);
    u = (u + 0x7FFFu + ((u >> 16) & 1u)) >> 16;   // RNE to bf16
    ((unsigned short*)(ws + OFF_WT_EN))[idx] = (unsigned short)u;
  }
  if (idx < 14400) {
    // dest idx = (e*9 + t)*25 + o ; src = conv2_k[(o*64 + e)*9 + t]
    int e = idx / 225, rem = idx % 225, t = rem / 25, o = rem % 25;
    ws[OFF_WC + idx] = conv2_k[(o * EE + e) * 9 + t];
  }
}

// ---------------------------------------------------------------------------
// border: zero-fill the pad border of ce_s (yy=0,161; xx=0,161).
// ---------------------------------------------------------------------------
__global__ __launch_bounds__(256) void fade_border(float* __restrict__ ces) {
  int idx = blockIdx.x * 256 + threadIdx.x;
  if (idx >= 82432) return;
  int e4 = idx & 3;
  int rest = idx >> 2;
  int posb = rest % 644;
  int rest2 = rest / 644;
  int q = rest2 & 3, b = rest2 >> 2;
  int yy, xx;
  if (posb < 162)      { yy = 0;   xx = posb; }
  else if (posb < 324) { yy = 161; xx = posb - 162; }
  else if (posb < 484) { xx = 0;   yy = posb - 324 + 1; }
  else                 { xx = 161; yy = posb - 484 + 1; }
  float4 z = make_float4(0.f, 0.f, 0.f, 0.f);
  *(float4*)(ces + ((((size_t)b * 4 + q) * 162 + yy) * 162 + xx) * 16 + e4 * 4) = z;
}

// ---------------------------------------------------------------------------
// conv1a: ce = 1x1(en) via bf16 MFMA (r14: measured win, total -23us).
// ---------------------------------------------------------------------------
__global__ __launch_bounds__(256) void fade_conv1a(
    const float* __restrict__ en, const float* __restrict__ b1_en,
    const unsigned short* __restrict__ BFu, float* __restrict__ ces) {
  __shared__ float buf[32][65];
  int bi = blockIdx.x;
  int b = bi / 400;
  int pos0 = (bi % 400) * 64;       // within batch plane (25600)
  int tid = threadIdx.x;
  int lane = tid & 63;
  int w = __builtin_amdgcn_readfirstlane(tid >> 6);   // 0..3
  int l15 = lane & 15, lg = lane >> 4;

  const float* ep = en + (size_t)b * CHN * 25600 + pos0;
  const bf16x8* BFF = (const bf16x8*)BFu;

  f32x4 acc0, acc1, acc2, acc3;
  { float bv = b1_en[l15];      acc0 = (f32x4){bv, bv, bv, bv}; }
  { float bv = b1_en[16 + l15]; acc1 = (f32x4){bv, bv, bv, bv}; }
  { float bv = b1_en[32 + l15]; acc2 = (f32x4){bv, bv, bv, bv}; }
  { float bv = b1_en[48 + l15]; acc3 = (f32x4){bv, bv, bv, bv}; }

  int cg = tid >> 6, po = tid & 63;
  for (int ks = 0; ks < 8; ++ks) {
    __syncthreads();
#pragma unroll
    for (int i = 0; i < 8; ++i) {
      int c = i * 4 + cg;
      buf[c][po] = ep[(size_t)(ks * 32 + c) * 25600 + po];
    }
    __syncthreads();
    bf16x8 av;
#define LDA_(j) { unsigned u = __float_as_uint(buf[lg * 8 + (j)][w * 16 + l15]); \
    u = (u + 0x7FFFu + ((u >> 16) & 1u)) >> 16; av[(j)] = (short)u; }
    LDA_(0) LDA_(1) LDA_(2) LDA_(3) LDA_(4) LDA_(5) LDA_(6) LDA_(7)
#undef LDA_
    const bf16x8* bp = BFF + ks * 256 + lane;
    bf16x8 b0 = bp[0], b1 = bp[64], b2 = bp[128], b3 = bp[192];
    acc0 = __builtin_amdgcn_mfma_f32_16x16x32_bf16(av, b0, acc0, 0, 0, 0);
    acc1 = __builtin_amdgcn_mfma_f32_16x16x32_bf16(av, b1, acc1, 0, 0, 0);
    acc2 = __builtin_amdgcn_mfma_f32_16x16x32_bf16(av, b2, acc2, 0, 0, 0);
    acc3 = __builtin_amdgcn_mfma_f32_16x16x32_bf16(av, b3, acc3, 0, 0, 0);
  }

  // scrambled write: ce_s[b][q][yy][xx][e'] = acc_full[4e'+q]; e = 4e'+q
  constexpr size_t QSTR = (size_t)162 * 162 * 16;
  float* cb = ces + (size_t)b * 4 * QSTR;
  int pbase = pos0 + w * 16 + lg * 4;
  int q = l15 & 3;
#define WR_(r) { int p = pbase + (r); int y = p / 160, x = p - y * 160; \
    size_t sb = (size_t)q * QSTR + (size_t)((y + 1) * 162 + (x + 1)) * 16 + (l15 >> 2); \
    cb[sb +  0] = acc0[(r)]; \
    cb[sb +  4] = acc1[(r)]; \
    cb[sb +  8] = acc2[(r)]; \
    cb[sb + 12] = acc3[(r)]; }
  WR_(0) WR_(1) WR_(2) WR_(3)
#undef WR_
}

// ---------------------------------------------------------------------------
// conv1b: cd = 1x1(de) -> padded cdg, + gate. Exact r7 part-B shape.
// ---------------------------------------------------------------------------
__global__ __launch_bounds__(256) void fade_conv1b(
    const float* __restrict__ de,
    const float* __restrict__ gate_w, const float* __restrict__ gate_b,
    const float* __restrict__ wt_de,
    float* __restrict__ cdg, float* __restrict__ gateo) {
  int tid = threadIdx.x;
  int id64 = tid & 63;
  int eg = __builtin_amdgcn_readfirstlane(tid >> 6);   // 0..3
  int pos = blockIdx.x * 64 + id64;
  if (pos >= NPB) return;

  int b = pos / (82 * 82), r = pos % (82 * 82);
  int yy = r / 82, xx = r % 82;
  int y = yy - 1, x = xx - 1;
  float* cop = cdg + (((size_t)b * 82 + yy) * 82 + xx) * 64 + eg * 16;
  if (y >= 0 && y < HH && x >= 0 && x < WW) {
    float acc[16];
#pragma unroll
    for (int e = 0; e < 16; ++e) acc[e] = 0.f;
    float g = gate_b[0];
    const float* dp = de + (size_t)b * CHN * HH * WW + (size_t)y * WW + x;
    float cur[8];
#pragma unroll
    for (int j = 0; j < 8; ++j) cur[j] = dp[(size_t)j * HH * WW];
    for (int c0 = 0; c0 < CHN; c0 += 8) {
      float nxt[8];
      if (c0 + 8 < CHN) {
#pragma unroll
        for (int j = 0; j < 8; ++j) nxt[j] = dp[(size_t)(c0 + 8 + j) * HH * WW];
      }
#pragma unroll
      for (int j = 0; j < 8; ++j) {
        float v = cur[j];
        const float* wr = wt_de + (c0 + j) * 64 + eg * 16;
#pragma unroll
        for (int e = 0; e < 16; ++e) acc[e] = fmaf(v, wr[e], acc[e]);
        g = fmaf(v, gate_w[c0 + j], g);
      }
      if (c0 + 8 < CHN) {
#pragma unroll
        for (int j = 0; j < 8; ++j) cur[j] = nxt[j];
      }
    }
#pragma unroll
    for (int m = 0; m < 4; ++m) {
      float4 v = make_float4(acc[4 * m], acc[4 * m + 1], acc[4 * m + 2], acc[4 * m + 3]);
      *(float4*)(cop + m * 4) = v;
    }
    if (eg == 0)
      gateo[((size_t)b * 80 + y) * 80 + x] = 1.f / (1.f + __expf(-g));
  } else {
    float4 z = make_float4(0.f, 0.f, 0.f, 0.f);
#pragma unroll
    for (int m = 0; m < 4; ++m) *(float4*)(cop + m * 4) = z;
  }
}

// ---------------------------------------------------------------------------
// kern: MERGED k_de+k_en tap loop (r13 win). Runtime d-loop (r8 lesson);
// two-phase LDS reduction (32KB).
// ---------------------------------------------------------------------------
__global__ __launch_bounds__(512) void fade_kern(
    const float* __restrict__ WC, const float* __restrict__ CES,
    const float* __restrict__ CDG, const float* __restrict__ conv2_b,
    float* __restrict__ KERN) {
  __shared__ float part[64 * 101];   // [row][(wv&3)*25+o], stride 101 (conflict-free)
  __shared__ float score[64 * 27];
  int bi = blockIdx.x;
  int b = bi / 400, t = bi % 400;
  int th0 = (t / 20) * 4, tw0 = (t % 20) * 4;
  int tid = threadIdx.x;
  int lane = tid & 63;
  int wv = __builtin_amdgcn_readfirstlane(tid >> 6);   // 0..7 K-slice
  int cell = lane >> 2, q = lane & 3;
  int h = th0 + (cell >> 2), w = tw0 + (cell & 3);

#define KDECL_(i) float a##i = 0.f;
  REP25(KDECL_)

#define KCH(val, base) { const float vv = (val); const float* wb = (base); \
    REP25(KFMA_) }
#define KFMA_(i) a##i = fmaf(vv, wb[(i)], a##i);

  // merged k_de + k_en over 9 taps; channels 8wv..8wv+8
  {
    int g = wv >> 1;
    const int pt = (g < 2) ? 1 : 0;
    const int pl = (g & 1) ? 0 : 1;
    const int eb = 8 * (wv & 1);
    for (int d = 0; d < 9; ++d) {
      int di = d / 3, dj = d - 3 * di;
      const float* cpd = CDG + (((size_t)b * 82 + (h + di)) * 82 + (w + dj)) * 64 + 8 * wv;
      float4 u0 = *(const float4*)(cpd);
      float4 u1 = *(const float4*)(cpd + 4);
      int yy = 2 * h + di - pt + 1;
      int xx = 2 * w + dj - pl + 1;
      const float* cpe = CES + ((((size_t)b * 4 + q) * 162 + yy) * 162 + xx) * 16 + eb;
      float4 v0 = *(const float4*)(cpe);
      float4 v1 = *(const float4*)(cpe + 4);
      const float* wt = WC + (8 * wv * 9 + d) * 25;
      KCH(u0.x + v0.x, wt)         KCH(u0.y + v0.y, wt + 225)
      KCH(u0.z + v0.z, wt + 450)   KCH(u0.w + v0.w, wt + 675)
      KCH(u1.x + v1.x, wt + 900)   KCH(u1.y + v1.y, wt + 1125)
      KCH(u1.z + v1.z, wt + 1350)  KCH(u1.w + v1.w, wt + 1575)
    }
  }

  {
    int pbase = lane * 101 + (wv & 3) * 25;
    if (wv < 4) {
#define KST_(i) part[pbase + (i)] = a##i;
      REP25(KST_)
    }
    __syncthreads();
    if (wv >= 4) {
#define KAD_(i) part[pbase + (i)] += a##i;
      REP25(KAD_)
    }
  }
  __syncthreads();

  {
    int row = tid & 63, sub = tid >> 6;
    int nO = (sub == 7) ? 4 : 3;
    for (int m = 0; m < nO; ++m) {
      int o = sub * 3 + m;
      float s = 0.f;
#pragma unroll
      for (int w4 = 0; w4 < 4; ++w4) s += part[row * 101 + w4 * 25 + o];
      score[row * 27 + o] = s + 2.f * conv2_b[o];   // bias in BOTH k_en and k_de
    }
  }
  __syncthreads();

  if (tid < 64) {
    int sbase = tid * 27;
#define SLD_(i) float s##i = score[sbase + (i)];
    REP25(SLD_)
    float mx = s0;
#define SMX_(i) mx = fmaxf(mx, s##i);
    REP25(SMX_)
    float sum = 0.f;
#define SEX_(i) s##i = __expf(s##i - mx); sum += s##i;
    REP25(SEX_)
    float inv = 1.f / sum;
    int cl = tid >> 2, qq = tid & 3;
    int hh = th0 + (cl >> 2), ww2 = tw0 + (cl & 3);
    float* kp = KERN + (size_t)(b * 6400 + hh * 80 + ww2) * 100;
#define SWR_(i) kp[(i) * 4 + qq] = s##i * inv;
    REP25(SWR_)
  }
}

// ---------------------------------------------------------------------------
// final: CARAFE + gate blend, r14 structure + LDS kern staging.
// r14 profile: VGPR=48 -> compiler remats the 25 float4 kern loads per
// j-iteration -> ~1.3GB of L2 re-reads, 42.7us. r15 (pre-scale) and r16
// (asm pin) both failed: remat persisted / pins serialized the loads.
// FIX per Guideline 3: stage the block's 32x25 float4 kern in LDS ONCE
// (kled[o][cell]: a wave's 32 cells read 512B contiguous = conflict-free
// ds_read_b128; half-waves broadcast). LDS 13.4+13.2 = 26.6KB.
// ---------------------------------------------------------------------------
__global__ __launch_bounds__(256) void fade_final(
    const float* __restrict__ en, const float* __restrict__ de,
    const float* __restrict__ KERN, const float* __restrict__ GATE,
    float* __restrict__ out) {
  __shared__ float sde[32 * 105];    // 32 channels x (8 rows x 13 cols pad)
  __shared__ float4 kled[25][33];    // [o][cell], pad 33 vs write conflicts
  int bi = blockIdx.x;
  int b = bi / 1600, r = bi % 1600;
  int t = r >> 3, cc = r & 7;
  int th0 = (t / 10) * 4, tw0 = (t % 10) * 8;
  int tid = threadIdx.x;
  int sg = tid >> 5, cell = tid & 31;
  int chh = cell >> 3, cw = cell & 7;
  int h = th0 + chh, w = tw0 + cw;

  // stage de: channels cc*32 .. +32, rows th0-2..+5, cols tw0-2..+9
  for (int kk = tid; kk < 3072; kk += 256) {
    int ci = kk / 96, rem = kk % 96, rr = rem / 12, c2 = rem % 12;
    int dr = th0 - 2 + rr, dc = tw0 - 2 + c2;
    float v = 0.f;
    if (dr >= 0 && dr < HH && dc >= 0 && dc < WW)
      v = de[((size_t)(b * CHN + cc * 32 + ci) * HH + dr) * WW + dc];
    sde[ci * 105 + rr * 13 + c2] = v;
  }
  // stage kern: 800 float4 (32 cells x 25 o), coalesced (o fastest)
  for (int kk = tid; kk < 800; kk += 256) {
    int cl2 = kk / 25, o = kk % 25;
    int hc = th0 + (cl2 >> 3), wc = tw0 + (cl2 & 7);
    kled[o][cl2] = *((const float4*)(KERN + (size_t)(b * 6400 + hc * 80 + wc) * 100) + o);
  }
  __syncthreads();

  float gv = GATE[((size_t)b * 80 + h) * 80 + w];
  float gv1 = 1.f - gv;

#pragma unroll
  for (int j = 0; j < 4; ++j) {
    int c = cc * 32 + sg * 4 + j;
    int sbase2 = (sg * 4 + j) * 105 + chh * 13 + cw;
#define FWD_(o) float w##o = sde[sbase2 + ((o) / 5) * 13 + ((o) % 5)];
    REP25(FWD_)
    float s00 = 0.f, s01 = 0.f, s10 = 0.f, s11 = 0.f;
#define FCF_(o) { float4 kv = kled[(o)][cell]; \
                  s00 = fmaf(w##o, kv.x, s00); s01 = fmaf(w##o, kv.y, s01); \
                  s10 = fmaf(w##o, kv.z, s10); s11 = fmaf(w##o, kv.w, s11); }
    REP25(FCF_)

    const float* ep = en + ((size_t)(b * CHN + c) * HO + 2 * h) * WO + 2 * w;
    float* op = out + ((size_t)(b * CHN + c) * HO + 2 * h) * WO + 2 * w;
    float2 e0 = *(const float2*)(ep);
    float2 e1 = *(const float2*)(ep + WO);
    float2 r0, r1;
    r0.x = fmaf(gv, e0.x, gv1 * s00);
    r0.y = fmaf(gv, e0.y, gv1 * s01);
    r1.x = fmaf(gv, e1.x, gv1 * s10);
    r1.y = fmaf(gv, e1.y, gv1 * s11);
    *(float2*)(op) = r0;
    *(float2*)(op + WO) = r1;
  }
}

// ---------------------------------------------------------------------------
extern "C" void kernel_launch(void* const* d_in, const int* in_sizes, int n_in,
                              void* d_out, int out_size, void* d_ws, size_t ws_size,
                              hipStream_t stream) {
  const float* en      = (const float*)d_in[0];
  const float* de      = (const float*)d_in[1];
  const float* gate_w  = (const float*)d_in[2];
  const float* gate_b  = (const float*)d_in[3];
  const float* w1_en   = (const float*)d_in[4];
  const float* b1_en   = (const float*)d_in[5];
  const float* w1_de   = (const float*)d_in[6];
  const float* conv2_k = (const float*)d_in[7];
  const float* conv2_b = (const float*)d_in[8];
  float* ws  = (float*)d_ws;
  float* out = (float*)d_out;

  const unsigned short* bfu = (const unsigned short*)(ws + OFF_WT_EN);
  float* wt_de = ws + OFF_WT_DE;
  float* wc    = ws + OFF_WC;
  float* cesb  = ws + OFF_CES;
  float* cdgb  = ws + OFF_CDG;
  float* gateo = ws + OFF_GATE;
  float* kernb = ws + OFF_KERN;

  hipLaunchKernelGGL(fade_prep,   dim3(64),   dim3(256), 0, stream, w1_en, w1_de, conv2_k, ws);
  hipLaunchKernelGGL(fade_border, dim3(322),  dim3(256), 0, stream, cesb);
  hipLaunchKernelGGL(fade_conv1a, dim3(800),  dim3(256), 0, stream, en, b1_en, bfu, cesb);
  hipLaunchKernelGGL(fade_conv1b, dim3(211),  dim3(256), 0, stream,
                     de, gate_w, gate_b, wt_de, cdgb, gateo);
  hipLaunchKernelGGL(fade_kern,   dim3(800),  dim3(512), 0, stream,
                     wc, cesb, cdgb, conv2_b, kernb);
  hipLaunchKernelGGL(fade_final,  dim3(3200), dim3(256), 0, stream,
                     en, de, kernb, gateo, out);
}

// Round 21
// 127.205 us; speedup vs baseline: 1.2437x; 1.0448x over previous
//
#include <hip/hip_runtime.h>
#include <hip/hip_bf16.h>

// Problem constants
constexpr int BB  = 2;
constexpr int CHN = 256;
constexpr int HH  = 80;
constexpr int WW  = 80;
constexpr int EE  = 64;
constexpr int HO  = 160;
constexpr int WO  = 160;

// Workspace layout (float offsets)
constexpr int OFF_WT_EN = 0;                    // BF bf16 B-fragments (16384 ushort = 8192 floats)
constexpr int OFF_WT_DE = 16384;                // [256][64]  w1_de transposed
constexpr int OFF_WC    = 32768;                // [64][3][3][25] conv2_k transposed
constexpr int OFF_CES   = 47168;                // [B][4][162][162][16] padded+scrambled ce
constexpr int CES_SZ    = 2 * 4 * 162 * 162 * 16;   // 3,359,232
constexpr int OFF_CDG   = OFF_CES + CES_SZ;     // [B][82][82][64] padded cd
constexpr int CDG_SZ    = 2 * 82 * 82 * 64;     // 860,672
constexpr int OFF_GATE  = OFF_CDG + CDG_SZ;     // [B][80][80]
constexpr int OFF_KERN  = OFF_GATE + 2 * 80 * 80;   // [B][80][80][25][4] softmaxed (o-major, q-minor!)

constexpr int NPB = BB * 82 * 82;     // 13448

using bf16x8 = __attribute__((ext_vector_type(8))) short;
using f32x4  = __attribute__((ext_vector_type(4))) float;

// X-macro: apply F to 0..24 (forces compile-time indices -> registers; rule #20)
#define REP25(F) F(0) F(1) F(2) F(3) F(4) F(5) F(6) F(7) F(8) F(9) F(10) F(11) \
                 F(12) F(13) F(14) F(15) F(16) F(17) F(18) F(19) F(20) F(21) F(22) F(23) F(24)

// ---------------------------------------------------------------------------
// Prep: wt_de transpose (conv1b), WC transpose (kern), and BF = bf16 MFMA
// B-fragments of w1_en for conv1a.
// ---------------------------------------------------------------------------
__global__ __launch_bounds__(256) void fade_prep(
    const float* __restrict__ w1_en, const float* __restrict__ w1_de,
    const float* __restrict__ conv2_k, float* __restrict__ ws) {
  int idx = blockIdx.x * 256 + threadIdx.x;
  if (idx < 16384) {
    int c = idx >> 6, e = idx & 63;           // dest = [c][e]
    ws[OFF_WT_DE + idx] = w1_de[e * CHN + c];
    // BF fragment (reuses old wt_en slot, as ushort)
    int j = idx & 7, l = (idx >> 3) & 63, et = (idx >> 9) & 3, ks = idx >> 11;
    int cc = ks * 32 + (l >> 4) * 8 + j;
    int ee = et * 16 + (l & 15);
    unsigned u = __float_as_uint(w1_en[ee * CHN + cc]);
    u = (u + 0x7FFFu + ((u >> 16) & 1u)) >> 16;   // RNE to bf16
    ((unsigned short*)(ws + OFF_WT_EN))[idx] = (unsigned short)u;
  }
  if (idx < 14400) {
    // dest idx = (e*9 + t)*25 + o ; src = conv2_k[(o*64 + e)*9 + t]
    int e = idx / 225, rem = idx % 225, t = rem / 25, o = rem % 25;
    ws[OFF_WC + idx] = conv2_k[(o * EE + e) * 9 + t];
  }
}

// ---------------------------------------------------------------------------
// border: zero-fill the pad border of ce_s (yy=0,161; xx=0,161).
// ---------------------------------------------------------------------------
__global__ __launch_bounds__(256) void fade_border(float* __restrict__ ces) {
  int idx = blockIdx.x * 256 + threadIdx.x;
  if (idx >= 82432) return;
  int e4 = idx & 3;
  int rest = idx >> 2;
  int posb = rest % 644;
  int rest2 = rest / 644;
  int q = rest2 & 3, b = rest2 >> 2;
  int yy, xx;
  if (posb < 162)      { yy = 0;   xx = posb; }
  else if (posb < 324) { yy = 161; xx = posb - 162; }
  else if (posb < 484) { xx = 0;   yy = posb - 324 + 1; }
  else                 { xx = 161; yy = posb - 484 + 1; }
  float4 z = make_float4(0.f, 0.f, 0.f, 0.f);
  *(float4*)(ces + ((((size_t)b * 4 + q) * 162 + yy) * 162 + xx) * 16 + e4 * 4) = z;
}

// ---------------------------------------------------------------------------
// conv1a: ce = 1x1(en) via bf16 MFMA (r14: measured win, total -23us).
// ---------------------------------------------------------------------------
__global__ __launch_bounds__(256) void fade_conv1a(
    const float* __restrict__ en, const float* __restrict__ b1_en,
    const unsigned short* __restrict__ BFu, float* __restrict__ ces) {
  __shared__ float buf[32][65];
  int bi = blockIdx.x;
  int b = bi / 400;
  int pos0 = (bi % 400) * 64;       // within batch plane (25600)
  int tid = threadIdx.x;
  int lane = tid & 63;
  int w = __builtin_amdgcn_readfirstlane(tid >> 6);   // 0..3
  int l15 = lane & 15, lg = lane >> 4;

  const float* ep = en + (size_t)b * CHN * 25600 + pos0;
  const bf16x8* BFF = (const bf16x8*)BFu;

  f32x4 acc0, acc1, acc2, acc3;
  { float bv = b1_en[l15];      acc0 = (f32x4){bv, bv, bv, bv}; }
  { float bv = b1_en[16 + l15]; acc1 = (f32x4){bv, bv, bv, bv}; }
  { float bv = b1_en[32 + l15]; acc2 = (f32x4){bv, bv, bv, bv}; }
  { float bv = b1_en[48 + l15]; acc3 = (f32x4){bv, bv, bv, bv}; }

  int cg = tid >> 6, po = tid & 63;
  for (int ks = 0; ks < 8; ++ks) {
    __syncthreads();
#pragma unroll
    for (int i = 0; i < 8; ++i) {
      int c = i * 4 + cg;
      buf[c][po] = ep[(size_t)(ks * 32 + c) * 25600 + po];
    }
    __syncthreads();
    bf16x8 av;
#define LDA_(j) { unsigned u = __float_as_uint(buf[lg * 8 + (j)][w * 16 + l15]); \
    u = (u + 0x7FFFu + ((u >> 16) & 1u)) >> 16; av[(j)] = (short)u; }
    LDA_(0) LDA_(1) LDA_(2) LDA_(3) LDA_(4) LDA_(5) LDA_(6) LDA_(7)
#undef LDA_
    const bf16x8* bp = BFF + ks * 256 + lane;
    bf16x8 b0 = bp[0], b1 = bp[64], b2 = bp[128], b3 = bp[192];
    acc0 = __builtin_amdgcn_mfma_f32_16x16x32_bf16(av, b0, acc0, 0, 0, 0);
    acc1 = __builtin_amdgcn_mfma_f32_16x16x32_bf16(av, b1, acc1, 0, 0, 0);
    acc2 = __builtin_amdgcn_mfma_f32_16x16x32_bf16(av, b2, acc2, 0, 0, 0);
    acc3 = __builtin_amdgcn_mfma_f32_16x16x32_bf16(av, b3, acc3, 0, 0, 0);
  }

  // scrambled write: ce_s[b][q][yy][xx][e'] = acc_full[4e'+q]; e = 4e'+q
  constexpr size_t QSTR = (size_t)162 * 162 * 16;
  float* cb = ces + (size_t)b * 4 * QSTR;
  int pbase = pos0 + w * 16 + lg * 4;
  int q = l15 & 3;
#define WR_(r) { int p = pbase + (r); int y = p / 160, x = p - y * 160; \
    size_t sb = (size_t)q * QSTR + (size_t)((y + 1) * 162 + (x + 1)) * 16 + (l15 >> 2); \
    cb[sb +  0] = acc0[(r)]; \
    cb[sb +  4] = acc1[(r)]; \
    cb[sb +  8] = acc2[(r)]; \
    cb[sb + 12] = acc3[(r)]; }
  WR_(0) WR_(1) WR_(2) WR_(3)
#undef WR_
}

// ---------------------------------------------------------------------------
// conv1b: cd = 1x1(de) -> padded cdg, + gate. Exact r7 part-B shape.
// ---------------------------------------------------------------------------
__global__ __launch_bounds__(256) void fade_conv1b(
    const float* __restrict__ de,
    const float* __restrict__ gate_w, const float* __restrict__ gate_b,
    const float* __restrict__ wt_de,
    float* __restrict__ cdg, float* __restrict__ gateo) {
  int tid = threadIdx.x;
  int id64 = tid & 63;
  int eg = __builtin_amdgcn_readfirstlane(tid >> 6);   // 0..3
  int pos = blockIdx.x * 64 + id64;
  if (pos >= NPB) return;

  int b = pos / (82 * 82), r = pos % (82 * 82);
  int yy = r / 82, xx = r % 82;
  int y = yy - 1, x = xx - 1;
  float* cop = cdg + (((size_t)b * 82 + yy) * 82 + xx) * 64 + eg * 16;
  if (y >= 0 && y < HH && x >= 0 && x < WW) {
    float acc[16];
#pragma unroll
    for (int e = 0; e < 16; ++e) acc[e] = 0.f;
    float g = gate_b[0];
    const float* dp = de + (size_t)b * CHN * HH * WW + (size_t)y * WW + x;
    float cur[8];
#pragma unroll
    for (int j = 0; j < 8; ++j) cur[j] = dp[(size_t)j * HH * WW];
    for (int c0 = 0; c0 < CHN; c0 += 8) {
      float nxt[8];
      if (c0 + 8 < CHN) {
#pragma unroll
        for (int j = 0; j < 8; ++j) nxt[j] = dp[(size_t)(c0 + 8 + j) * HH * WW];
      }
#pragma unroll
      for (int j = 0; j < 8; ++j) {
        float v = cur[j];
        const float* wr = wt_de + (c0 + j) * 64 + eg * 16;
#pragma unroll
        for (int e = 0; e < 16; ++e) acc[e] = fmaf(v, wr[e], acc[e]);
        g = fmaf(v, gate_w[c0 + j], g);
      }
      if (c0 + 8 < CHN) {
#pragma unroll
        for (int j = 0; j < 8; ++j) cur[j] = nxt[j];
      }
    }
#pragma unroll
    for (int m = 0; m < 4; ++m) {
      float4 v = make_float4(acc[4 * m], acc[4 * m + 1], acc[4 * m + 2], acc[4 * m + 3]);
      *(float4*)(cop + m * 4) = v;
    }
    if (eg == 0)
      gateo[((size_t)b * 80 + y) * 80 + x] = 1.f / (1.f + __expf(-g));
  } else {
    float4 z = make_float4(0.f, 0.f, 0.f, 0.f);
#pragma unroll
    for (int m = 0; m < 4; ++m) *(float4*)(cop + m * 4) = z;
  }
}

// ---------------------------------------------------------------------------
// kern: MERGED k_de+k_en tap loop (r13 win) + 2-STAGE SOFTWARE PIPELINE:
// r18 profile (40.8us, VALU 31%, all traffic L2-resident, no spill) =>
// stall is L2 latency at the top of each d-iter (4 dependent float4 loads).
// Prefetch d+1's u/v during d's 200-FMA chain (conv1b's cur/nxt idiom).
// Live-set grows by exactly 16 regs -- bounded, unlike r8's full unroll.
// Runtime d-loop retained; two-phase LDS reduction (32KB) retained.
// ---------------------------------------------------------------------------
__global__ __launch_bounds__(512) void fade_kern(
    const float* __restrict__ WC, const float* __restrict__ CES,
    const float* __restrict__ CDG, const float* __restrict__ conv2_b,
    float* __restrict__ KERN) {
  __shared__ float part[64 * 101];   // [row][(wv&3)*25+o], stride 101 (conflict-free)
  __shared__ float score[64 * 27];
  int bi = blockIdx.x;
  int b = bi / 400, t = bi % 400;
  int th0 = (t / 20) * 4, tw0 = (t % 20) * 4;
  int tid = threadIdx.x;
  int lane = tid & 63;
  int wv = __builtin_amdgcn_readfirstlane(tid >> 6);   // 0..7 K-slice
  int cell = lane >> 2, q = lane & 3;
  int h = th0 + (cell >> 2), w = tw0 + (cell & 3);

#define KDECL_(i) float a##i = 0.f;
  REP25(KDECL_)

#define KCH(val, base) { const float vv = (val); const float* wb = (base); \
    REP25(KFMA_) }
#define KFMA_(i) a##i = fmaf(vv, wb[(i)], a##i);

  // merged k_de + k_en over 9 taps; channels 8wv..8wv+8; 2-stage pipeline
  {
    int g = wv >> 1;
    const int pt = (g < 2) ? 1 : 0;
    const int pl = (g & 1) ? 0 : 1;
    const int eb = 8 * (wv & 1);
    const float* cpd_base = CDG + (((size_t)b * 82 + h) * 82 + w) * 64 + 8 * wv;
    const float* cpe_base = CES + ((((size_t)b * 4 + q) * 162 + (2 * h + 1 - pt)) * 162 +
                                   (2 * w + 1 - pl)) * 16 + eb;
    float4 u0 = *(const float4*)(cpd_base);
    float4 u1 = *(const float4*)(cpd_base + 4);
    float4 v0 = *(const float4*)(cpe_base);
    float4 v1 = *(const float4*)(cpe_base + 4);
    for (int d = 0; d < 9; ++d) {
      float4 nu0, nu1, nv0, nv1;
      if (d < 8) {
        int dn = d + 1;
        int di = dn / 3, dj = dn - 3 * di;       // wave-uniform SALU
        const float* cpd = cpd_base + (di * 82 + dj) * 64;
        const float* cpe = cpe_base + (di * 162 + dj) * 16;
        nu0 = *(const float4*)(cpd);
        nu1 = *(const float4*)(cpd + 4);
        nv0 = *(const float4*)(cpe);
        nv1 = *(const float4*)(cpe + 4);
      }
      const float* wt = WC + (8 * wv * 9 + d) * 25;
      KCH(u0.x + v0.x, wt)         KCH(u0.y + v0.y, wt + 225)
      KCH(u0.z + v0.z, wt + 450)   KCH(u0.w + v0.w, wt + 675)
      KCH(u1.x + v1.x, wt + 900)   KCH(u1.y + v1.y, wt + 1125)
      KCH(u1.z + v1.z, wt + 1350)  KCH(u1.w + v1.w, wt + 1575)
      if (d < 8) { u0 = nu0; u1 = nu1; v0 = nv0; v1 = nv1; }
    }
  }

  {
    int pbase = lane * 101 + (wv & 3) * 25;
    if (wv < 4) {
#define KST_(i) part[pbase + (i)] = a##i;
      REP25(KST_)
    }
    __syncthreads();
    if (wv >= 4) {
#define KAD_(i) part[pbase + (i)] += a##i;
      REP25(KAD_)
    }
  }
  __syncthreads();

  {
    int row = tid & 63, sub = tid >> 6;
    int nO = (sub == 7) ? 4 : 3;
    for (int m = 0; m < nO; ++m) {
      int o = sub * 3 + m;
      float s = 0.f;
#pragma unroll
      for (int w4 = 0; w4 < 4; ++w4) s += part[row * 101 + w4 * 25 + o];
      score[row * 27 + o] = s + 2.f * conv2_b[o];   // bias in BOTH k_en and k_de
    }
  }
  __syncthreads();

  if (tid < 64) {
    int sbase = tid * 27;
#define SLD_(i) float s##i = score[sbase + (i)];
    REP25(SLD_)
    float mx = s0;
#define SMX_(i) mx = fmaxf(mx, s##i);
    REP25(SMX_)
    float sum = 0.f;
#define SEX_(i) s##i = __expf(s##i - mx); sum += s##i;
    REP25(SEX_)
    float inv = 1.f / sum;
    int cl = tid >> 2, qq = tid & 3;
    int hh = th0 + (cl >> 2), ww2 = tw0 + (cl & 3);
    float* kp = KERN + (size_t)(b * 6400 + hh * 80 + ww2) * 100;
#define SWR_(i) kp[(i) * 4 + qq] = s##i * inv;
    REP25(SWR_)
  }
}

// ---------------------------------------------------------------------------
// final: CARAFE + gate blend, r18 structure (LDS kern staging -- measured
// win vs r14/r15/r16 register-allocator battles).
// ---------------------------------------------------------------------------
__global__ __launch_bounds__(256) void fade_final(
    const float* __restrict__ en, const float* __restrict__ de,
    const float* __restrict__ KERN, const float* __restrict__ GATE,
    float* __restrict__ out) {
  __shared__ float sde[32 * 105];    // 32 channels x (8 rows x 13 cols pad)
  __shared__ float4 kled[25][33];    // [o][cell], pad 33 vs write conflicts
  int bi = blockIdx.x;
  int b = bi / 1600, r = bi % 1600;
  int t = r >> 3, cc = r & 7;
  int th0 = (t / 10) * 4, tw0 = (t % 10) * 8;
  int tid = threadIdx.x;
  int sg = tid >> 5, cell = tid & 31;
  int chh = cell >> 3, cw = cell & 7;
  int h = th0 + chh, w = tw0 + cw;

  // stage de: channels cc*32 .. +32, rows th0-2..+5, cols tw0-2..+9
  for (int kk = tid; kk < 3072; kk += 256) {
    int ci = kk / 96, rem = kk % 96, rr = rem / 12, c2 = rem % 12;
    int dr = th0 - 2 + rr, dc = tw0 - 2 + c2;
    float v = 0.f;
    if (dr >= 0 && dr < HH && dc >= 0 && dc < WW)
      v = de[((size_t)(b * CHN + cc * 32 + ci) * HH + dr) * WW + dc];
    sde[ci * 105 + rr * 13 + c2] = v;
  }
  // stage kern: 800 float4 (32 cells x 25 o), coalesced (o fastest)
  for (int kk = tid; kk < 800; kk += 256) {
    int cl2 = kk / 25, o = kk % 25;
    int hc = th0 + (cl2 >> 3), wc = tw0 + (cl2 & 7);
    kled[o][cl2] = *((const float4*)(KERN + (size_t)(b * 6400 + hc * 80 + wc) * 100) + o);
  }
  __syncthreads();

  float gv = GATE[((size_t)b * 80 + h) * 80 + w];
  float gv1 = 1.f - gv;

#pragma unroll
  for (int j = 0; j < 4; ++j) {
    int c = cc * 32 + sg * 4 + j;
    int sbase2 = (sg * 4 + j) * 105 + chh * 13 + cw;
#define FWD_(o) float w##o = sde[sbase2 + ((o) / 5) * 13 + ((o) % 5)];
    REP25(FWD_)
    float s00 = 0.f, s01 = 0.f, s10 = 0.f, s11 = 0.f;
#define FCF_(o) { float4 kv = kled[(o)][cell]; \
                  s00 = fmaf(w##o, kv.x, s00); s01 = fmaf(w##o, kv.y, s01); \
                  s10 = fmaf(w##o, kv.z, s10); s11 = fmaf(w##o, kv.w, s11); }
    REP25(FCF_)

    const float* ep = en + ((size_t)(b * CHN + c) * HO + 2 * h) * WO + 2 * w;
    float* op = out + ((size_t)(b * CHN + c) * HO + 2 * h) * WO + 2 * w;
    float2 e0 = *(const float2*)(ep);
    float2 e1 = *(const float2*)(ep + WO);
    float2 r0, r1;
    r0.x = fmaf(gv, e0.x, gv1 * s00);
    r0.y = fmaf(gv, e0.y, gv1 * s01);
    r1.x = fmaf(gv, e1.x, gv1 * s10);
    r1.y = fmaf(gv, e1.y, gv1 * s11);
    *(float2*)(op) = r0;
    *(float2*)(op + WO) = r1;
  }
}

// ---------------------------------------------------------------------------
extern "C" void kernel_launch(void* const* d_in, const int* in_sizes, int n_in,
                              void* d_out, int out_size, void* d_ws, size_t ws_size,
                              hipStream_t stream) {
  const float* en      = (const float*)d_in[0];
  const float* de      = (const float*)d_in[1];
  const float* gate_w  = (const float*)d_in[2];
  const float* gate_b  = (const float*)d_in[3];
  const float* w1_en   = (const float*)d_in[4];
  const float* b1_en   = (const float*)d_in[5];
  const float* w1_de   = (const float*)d_in[6];
  const float* conv2_k = (const float*)d_in[7];
  const float* conv2_b = (const float*)d_in[8];
  float* ws  = (float*)d_ws;
  float* out = (float*)d_out;

  const unsigned short* bfu = (const unsigned short*)(ws + OFF_WT_EN);
  float* wt_de = ws + OFF_WT_DE;
  float* wc    = ws + OFF_WC;
  float* cesb  = ws + OFF_CES;
  float* cdgb  = ws + OFF_CDG;
  float* gateo = ws + OFF_GATE;
  float* kernb = ws + OFF_KERN;

  hipLaunchKernelGGL(fade_prep,   dim3(64),   dim3(256), 0, stream, w1_en, w1_de, conv2_k, ws);
  hipLaunchKernelGGL(fade_border, dim3(322),  dim3(256), 0, stream, cesb);
  hipLaunchKernelGGL(fade_conv1a, dim3(800),  dim3(256), 0, stream, en, b1_en, bfu, cesb);
  hipLaunchKernelGGL(fade_conv1b, dim3(211),  dim3(256), 0, stream,
                     de, gate_w, gate_b, wt_de, cdgb, gateo);
  hipLaunchKernelGGL(fade_kern,   dim3(800),  dim3(512), 0, stream,
                     wc, cesb, cdgb, conv2_b, kernb);
  hipLaunchKernelGGL(fade_final,  dim3(3200), dim3(256), 0, stream,
                     en, de, kernb, gateo, out);
}

// Round 22
// 123.766 us; speedup vs baseline: 1.2782x; 1.0278x over previous
//
#include <hip/hip_runtime.h>
#include <hip/hip_bf16.h>

// Problem constants
constexpr int BB  = 2;
constexpr int CHN = 256;
constexpr int HH  = 80;
constexpr int WW  = 80;
constexpr int EE  = 64;
constexpr int HO  = 160;
constexpr int WO  = 160;

// Workspace layout (float offsets)
constexpr int OFF_WT_EN = 0;                    // BF bf16 B-fragments (16384 ushort = 8192 floats)
constexpr int OFF_WT_DE = 16384;                // [256][64]  w1_de transposed
constexpr int OFF_WC    = 32768;                // [64][3][3][25] conv2_k transposed
constexpr int OFF_CES   = 47168;                // [B][4][162][162][16] padded+scrambled ce
constexpr int CES_SZ    = 2 * 4 * 162 * 162 * 16;   // 3,359,232
constexpr int OFF_CDG   = OFF_CES + CES_SZ;     // [B][82][82][64] padded cd
constexpr int CDG_SZ    = 2 * 82 * 82 * 64;     // 860,672
constexpr int OFF_GATE  = OFF_CDG + CDG_SZ;     // [B][80][80]
constexpr int OFF_KERN  = OFF_GATE + 2 * 80 * 80;   // [B][80][80][25][4] softmaxed (o-major, q-minor!)

constexpr int NPB = BB * 82 * 82;     // 13448

using bf16x8 = __attribute__((ext_vector_type(8))) short;
using f32x4  = __attribute__((ext_vector_type(4))) float;

// X-macro: apply F to 0..24 (forces compile-time indices -> registers; rule #20)
#define REP25(F) F(0) F(1) F(2) F(3) F(4) F(5) F(6) F(7) F(8) F(9) F(10) F(11) \
                 F(12) F(13) F(14) F(15) F(16) F(17) F(18) F(19) F(20) F(21) F(22) F(23) F(24)

// ---------------------------------------------------------------------------
// prep+border merged (r22: one fewer launch; disjoint writes, zero risk):
//   - wt_de transpose (conv1b), WC transpose (kern), BF bf16 frags (conv1a)
//   - zero-fill ce_s pad border (yy/xx == 0 or 161)
// Grid = 322 blocks of 256.
// ---------------------------------------------------------------------------
__global__ __launch_bounds__(256) void fade_prep(
    const float* __restrict__ w1_en, const float* __restrict__ w1_de,
    const float* __restrict__ conv2_k, float* __restrict__ ws,
    float* __restrict__ ces) {
  int idx = blockIdx.x * 256 + threadIdx.x;
  if (idx < 16384) {
    int c = idx >> 6, e = idx & 63;           // dest = [c][e]
    ws[OFF_WT_DE + idx] = w1_de[e * CHN + c];
    // BF fragment (reuses old wt_en slot, as ushort)
    int j = idx & 7, l = (idx >> 3) & 63, et = (idx >> 9) & 3, ks = idx >> 11;
    int cc = ks * 32 + (l >> 4) * 8 + j;
    int ee = et * 16 + (l & 15);
    unsigned u = __float_as_uint(w1_en[ee * CHN + cc]);
    u = (u + 0x7FFFu + ((u >> 16) & 1u)) >> 16;   // RNE to bf16
    ((unsigned short*)(ws + OFF_WT_EN))[idx] = (unsigned short)u;
  }
  if (idx < 14400) {
    // dest idx = (e*9 + t)*25 + o ; src = conv2_k[(o*64 + e)*9 + t]
    int e = idx / 225, rem = idx % 225, t = rem / 25, o = rem % 25;
    ws[OFF_WC + idx] = conv2_k[(o * EE + e) * 9 + t];
  }
  if (idx < 82432) {
    int e4 = idx & 3;
    int rest = idx >> 2;
    int posb = rest % 644;
    int rest2 = rest / 644;
    int q = rest2 & 3, b = rest2 >> 2;
    int yy, xx;
    if (posb < 162)      { yy = 0;   xx = posb; }
    else if (posb < 324) { yy = 161; xx = posb - 162; }
    else if (posb < 484) { xx = 0;   yy = posb - 324 + 1; }
    else                 { xx = 161; yy = posb - 484 + 1; }
    float4 z = make_float4(0.f, 0.f, 0.f, 0.f);
    *(float4*)(ces + ((((size_t)b * 4 + q) * 162 + yy) * 162 + xx) * 16 + e4 * 4) = z;
  }
}

// ---------------------------------------------------------------------------
// conv1a: ce = 1x1(en) via bf16 MFMA (r14 win), now DOUBLE-BUFFERED staging:
// old loop was {sync; load; sync; compute} x8 -- loads never overlap compute
// and every barrier drains vmcnt (guide §5 barrier-drain stall). New loop:
// prologue-load ks=0; then {issue load(ks+1) into buf[p^1]; compute buf[p];
// sync} -- one barrier/iter, staging hidden under 4 MFMAs + cvt chain.
// LDS 16.6 -> 33.3KB (4 blocks/CU vs 8; occupancy counter WILL drop -- the
// signal is dur). Same addresses, same arithmetic.
// ---------------------------------------------------------------------------
__global__ __launch_bounds__(256) void fade_conv1a(
    const float* __restrict__ en, const float* __restrict__ b1_en,
    const unsigned short* __restrict__ BFu, float* __restrict__ ces) {
  __shared__ float buf[2][32][65];
  int bi = blockIdx.x;
  int b = bi / 400;
  int pos0 = (bi % 400) * 64;       // within batch plane (25600)
  int tid = threadIdx.x;
  int lane = tid & 63;
  int w = __builtin_amdgcn_readfirstlane(tid >> 6);   // 0..3
  int l15 = lane & 15, lg = lane >> 4;

  const float* ep = en + (size_t)b * CHN * 25600 + pos0;
  const bf16x8* BFF = (const bf16x8*)BFu;

  f32x4 acc0, acc1, acc2, acc3;
  { float bv = b1_en[l15];      acc0 = (f32x4){bv, bv, bv, bv}; }
  { float bv = b1_en[16 + l15]; acc1 = (f32x4){bv, bv, bv, bv}; }
  { float bv = b1_en[32 + l15]; acc2 = (f32x4){bv, bv, bv, bv}; }
  { float bv = b1_en[48 + l15]; acc3 = (f32x4){bv, bv, bv, bv}; }

  int cg = tid >> 6, po = tid & 63;
  // prologue: stage ks=0
#pragma unroll
  for (int i = 0; i < 8; ++i) {
    int c = i * 4 + cg;
    buf[0][c][po] = ep[(size_t)c * 25600 + po];
  }
  __syncthreads();

  for (int ks = 0; ks < 8; ++ks) {
    int p = ks & 1;
    if (ks < 7) {
      // issue next tile's loads; overlaps the compute below. Writing
      // buf[p^1] is safe: its readers finished before last iter's barrier.
#pragma unroll
      for (int i = 0; i < 8; ++i) {
        int c = i * 4 + cg;
        buf[p ^ 1][c][po] = ep[(size_t)((ks + 1) * 32 + c) * 25600 + po];
      }
    }
    bf16x8 av;
#define LDA_(j) { unsigned u = __float_as_uint(buf[p][lg * 8 + (j)][w * 16 + l15]); \
    u = (u + 0x7FFFu + ((u >> 16) & 1u)) >> 16; av[(j)] = (short)u; }
    LDA_(0) LDA_(1) LDA_(2) LDA_(3) LDA_(4) LDA_(5) LDA_(6) LDA_(7)
#undef LDA_
    const bf16x8* bp = BFF + ks * 256 + lane;
    bf16x8 b0 = bp[0], b1 = bp[64], b2 = bp[128], b3 = bp[192];
    acc0 = __builtin_amdgcn_mfma_f32_16x16x32_bf16(av, b0, acc0, 0, 0, 0);
    acc1 = __builtin_amdgcn_mfma_f32_16x16x32_bf16(av, b1, acc1, 0, 0, 0);
    acc2 = __builtin_amdgcn_mfma_f32_16x16x32_bf16(av, b2, acc2, 0, 0, 0);
    acc3 = __builtin_amdgcn_mfma_f32_16x16x32_bf16(av, b3, acc3, 0, 0, 0);
    __syncthreads();
  }

  // scrambled write: ce_s[b][q][yy][xx][e'] = acc_full[4e'+q]; e = 4e'+q
  constexpr size_t QSTR = (size_t)162 * 162 * 16;
  float* cb = ces + (size_t)b * 4 * QSTR;
  int pbase = pos0 + w * 16 + lg * 4;
  int q = l15 & 3;
#define WR_(r) { int p2 = pbase + (r); int y = p2 / 160, x = p2 - y * 160; \
    size_t sb = (size_t)q * QSTR + (size_t)((y + 1) * 162 + (x + 1)) * 16 + (l15 >> 2); \
    cb[sb +  0] = acc0[(r)]; \
    cb[sb +  4] = acc1[(r)]; \
    cb[sb +  8] = acc2[(r)]; \
    cb[sb + 12] = acc3[(r)]; }
  WR_(0) WR_(1) WR_(2) WR_(3)
#undef WR_
}

// ---------------------------------------------------------------------------
// conv1b: cd = 1x1(de) -> padded cdg, + gate. Exact r7 part-B shape.
// ---------------------------------------------------------------------------
__global__ __launch_bounds__(256) void fade_conv1b(
    const float* __restrict__ de,
    const float* __restrict__ gate_w, const float* __restrict__ gate_b,
    const float* __restrict__ wt_de,
    float* __restrict__ cdg, float* __restrict__ gateo) {
  int tid = threadIdx.x;
  int id64 = tid & 63;
  int eg = __builtin_amdgcn_readfirstlane(tid >> 6);   // 0..3
  int pos = blockIdx.x * 64 + id64;
  if (pos >= NPB) return;

  int b = pos / (82 * 82), r = pos % (82 * 82);
  int yy = r / 82, xx = r % 82;
  int y = yy - 1, x = xx - 1;
  float* cop = cdg + (((size_t)b * 82 + yy) * 82 + xx) * 64 + eg * 16;
  if (y >= 0 && y < HH && x >= 0 && x < WW) {
    float acc[16];
#pragma unroll
    for (int e = 0; e < 16; ++e) acc[e] = 0.f;
    float g = gate_b[0];
    const float* dp = de + (size_t)b * CHN * HH * WW + (size_t)y * WW + x;
    float cur[8];
#pragma unroll
    for (int j = 0; j < 8; ++j) cur[j] = dp[(size_t)j * HH * WW];
    for (int c0 = 0; c0 < CHN; c0 += 8) {
      float nxt[8];
      if (c0 + 8 < CHN) {
#pragma unroll
        for (int j = 0; j < 8; ++j) nxt[j] = dp[(size_t)(c0 + 8 + j) * HH * WW];
      }
#pragma unroll
      for (int j = 0; j < 8; ++j) {
        float v = cur[j];
        const float* wr = wt_de + (c0 + j) * 64 + eg * 16;
#pragma unroll
        for (int e = 0; e < 16; ++e) acc[e] = fmaf(v, wr[e], acc[e]);
        g = fmaf(v, gate_w[c0 + j], g);
      }
      if (c0 + 8 < CHN) {
#pragma unroll
        for (int j = 0; j < 8; ++j) cur[j] = nxt[j];
      }
    }
#pragma unroll
    for (int m = 0; m < 4; ++m) {
      float4 v = make_float4(acc[4 * m], acc[4 * m + 1], acc[4 * m + 2], acc[4 * m + 3]);
      *(float4*)(cop + m * 4) = v;
    }
    if (eg == 0)
      gateo[((size_t)b * 80 + y) * 80 + x] = 1.f / (1.f + __expf(-g));
  } else {
    float4 z = make_float4(0.f, 0.f, 0.f, 0.f);
#pragma unroll
    for (int m = 0; m < 4; ++m) *(float4*)(cop + m * 4) = z;
  }
}

// ---------------------------------------------------------------------------
// kern: MERGED k_de+k_en tap loop (r13 win) + 2-stage pipeline (r21 win).
// Runtime d-loop retained; two-phase LDS reduction (32KB) retained.
// ---------------------------------------------------------------------------
__global__ __launch_bounds__(512) void fade_kern(
    const float* __restrict__ WC, const float* __restrict__ CES,
    const float* __restrict__ CDG, const float* __restrict__ conv2_b,
    float* __restrict__ KERN) {
  __shared__ float part[64 * 101];   // [row][(wv&3)*25+o], stride 101 (conflict-free)
  __shared__ float score[64 * 27];
  int bi = blockIdx.x;
  int b = bi / 400, t = bi % 400;
  int th0 = (t / 20) * 4, tw0 = (t % 20) * 4;
  int tid = threadIdx.x;
  int lane = tid & 63;
  int wv = __builtin_amdgcn_readfirstlane(tid >> 6);   // 0..7 K-slice
  int cell = lane >> 2, q = lane & 3;
  int h = th0 + (cell >> 2), w = tw0 + (cell & 3);

#define KDECL_(i) float a##i = 0.f;
  REP25(KDECL_)

#define KCH(val, base) { const float vv = (val); const float* wb = (base); \
    REP25(KFMA_) }
#define KFMA_(i) a##i = fmaf(vv, wb[(i)], a##i);

  // merged k_de + k_en over 9 taps; channels 8wv..8wv+8; 2-stage pipeline
  {
    int g = wv >> 1;
    const int pt = (g < 2) ? 1 : 0;
    const int pl = (g & 1) ? 0 : 1;
    const int eb = 8 * (wv & 1);
    const float* cpd_base = CDG + (((size_t)b * 82 + h) * 82 + w) * 64 + 8 * wv;
    const float* cpe_base = CES + ((((size_t)b * 4 + q) * 162 + (2 * h + 1 - pt)) * 162 +
                                   (2 * w + 1 - pl)) * 16 + eb;
    float4 u0 = *(const float4*)(cpd_base);
    float4 u1 = *(const float4*)(cpd_base + 4);
    float4 v0 = *(const float4*)(cpe_base);
    float4 v1 = *(const float4*)(cpe_base + 4);
    for (int d = 0; d < 9; ++d) {
      float4 nu0, nu1, nv0, nv1;
      if (d < 8) {
        int dn = d + 1;
        int di = dn / 3, dj = dn - 3 * di;       // wave-uniform SALU
        const float* cpd = cpd_base + (di * 82 + dj) * 64;
        const float* cpe = cpe_base + (di * 162 + dj) * 16;
        nu0 = *(const float4*)(cpd);
        nu1 = *(const float4*)(cpd + 4);
        nv0 = *(const float4*)(cpe);
        nv1 = *(const float4*)(cpe + 4);
      }
      const float* wt = WC + (8 * wv * 9 + d) * 25;
      KCH(u0.x + v0.x, wt)         KCH(u0.y + v0.y, wt + 225)
      KCH(u0.z + v0.z, wt + 450)   KCH(u0.w + v0.w, wt + 675)
      KCH(u1.x + v1.x, wt + 900)   KCH(u1.y + v1.y, wt + 1125)
      KCH(u1.z + v1.z, wt + 1350)  KCH(u1.w + v1.w, wt + 1575)
      if (d < 8) { u0 = nu0; u1 = nu1; v0 = nv0; v1 = nv1; }
    }
  }

  {
    int pbase = lane * 101 + (wv & 3) * 25;
    if (wv < 4) {
#define KST_(i) part[pbase + (i)] = a##i;
      REP25(KST_)
    }
    __syncthreads();
    if (wv >= 4) {
#define KAD_(i) part[pbase + (i)] += a##i;
      REP25(KAD_)
    }
  }
  __syncthreads();

  {
    int row = tid & 63, sub = tid >> 6;
    int nO = (sub == 7) ? 4 : 3;
    for (int m = 0; m < nO; ++m) {
      int o = sub * 3 + m;
      float s = 0.f;
#pragma unroll
      for (int w4 = 0; w4 < 4; ++w4) s += part[row * 101 + w4 * 25 + o];
      score[row * 27 + o] = s + 2.f * conv2_b[o];   // bias in BOTH k_en and k_de
    }
  }
  __syncthreads();

  if (tid < 64) {
    int sbase = tid * 27;
#define SLD_(i) float s##i = score[sbase + (i)];
    REP25(SLD_)
    float mx = s0;
#define SMX_(i) mx = fmaxf(mx, s##i);
    REP25(SMX_)
    float sum = 0.f;
#define SEX_(i) s##i = __expf(s##i - mx); sum += s##i;
    REP25(SEX_)
    float inv = 1.f / sum;
    int cl = tid >> 2, qq = tid & 3;
    int hh = th0 + (cl >> 2), ww2 = tw0 + (cl & 3);
    float* kp = KERN + (size_t)(b * 6400 + hh * 80 + ww2) * 100;
#define SWR_(i) kp[(i) * 4 + qq] = s##i * inv;
    REP25(SWR_)
  }
}

// ---------------------------------------------------------------------------
// final: CARAFE + gate blend, r18 structure (LDS kern staging -- measured
// win vs r14/r15/r16 register-allocator battles).
// ---------------------------------------------------------------------------
__global__ __launch_bounds__(256) void fade_final(
    const float* __restrict__ en, const float* __restrict__ de,
    const float* __restrict__ KERN, const float* __restrict__ GATE,
    float* __restrict__ out) {
  __shared__ float sde[32 * 105];    // 32 channels x (8 rows x 13 cols pad)
  __shared__ float4 kled[25][33];    // [o][cell], pad 33 vs write conflicts
  int bi = blockIdx.x;
  int b = bi / 1600, r = bi % 1600;
  int t = r >> 3, cc = r & 7;
  int th0 = (t / 10) * 4, tw0 = (t % 10) * 8;
  int tid = threadIdx.x;
  int sg = tid >> 5, cell = tid & 31;
  int chh = cell >> 3, cw = cell & 7;
  int h = th0 + chh, w = tw0 + cw;

  // stage de: channels cc*32 .. +32, rows th0-2..+5, cols tw0-2..+9
  for (int kk = tid; kk < 3072; kk += 256) {
    int ci = kk / 96, rem = kk % 96, rr = rem / 12, c2 = rem % 12;
    int dr = th0 - 2 + rr, dc = tw0 - 2 + c2;
    float v = 0.f;
    if (dr >= 0 && dr < HH && dc >= 0 && dc < WW)
      v = de[((size_t)(b * CHN + cc * 32 + ci) * HH + dr) * WW + dc];
    sde[ci * 105 + rr * 13 + c2] = v;
  }
  // stage kern: 800 float4 (32 cells x 25 o), coalesced (o fastest)
  for (int kk = tid; kk < 800; kk += 256) {
    int cl2 = kk / 25, o = kk % 25;
    int hc = th0 + (cl2 >> 3), wc = tw0 + (cl2 & 7);
    kled[o][cl2] = *((const float4*)(KERN + (size_t)(b * 6400 + hc * 80 + wc) * 100) + o);
  }
  __syncthreads();

  float gv = GATE[((size_t)b * 80 + h) * 80 + w];
  float gv1 = 1.f - gv;

#pragma unroll
  for (int j = 0; j < 4; ++j) {
    int c = cc * 32 + sg * 4 + j;
    int sbase2 = (sg * 4 + j) * 105 + chh * 13 + cw;
#define FWD_(o) float w##o = sde[sbase2 + ((o) / 5) * 13 + ((o) % 5)];
    REP25(FWD_)
    float s00 = 0.f, s01 = 0.f, s10 = 0.f, s11 = 0.f;
#define FCF_(o) { float4 kv = kled[(o)][cell]; \
                  s00 = fmaf(w##o, kv.x, s00); s01 = fmaf(w##o, kv.y, s01); \
                  s10 = fmaf(w##o, kv.z, s10); s11 = fmaf(w##o, kv.w, s11); }
    REP25(FCF_)

    const float* ep = en + ((size_t)(b * CHN + c) * HO + 2 * h) * WO + 2 * w;
    float* op = out + ((size_t)(b * CHN + c) * HO + 2 * h) * WO + 2 * w;
    float2 e0 = *(const float2*)(ep);
    float2 e1 = *(const float2*)(ep + WO);
    float2 r0, r1;
    r0.x = fmaf(gv, e0.x, gv1 * s00);
    r0.y = fmaf(gv, e0.y, gv1 * s01);
    r1.x = fmaf(gv, e1.x, gv1 * s10);
    r1.y = fmaf(gv, e1.y, gv1 * s11);
    *(float2*)(op) = r0;
    *(float2*)(op + WO) = r1;
  }
}

// ---------------------------------------------------------------------------
extern "C" void kernel_launch(void* const* d_in, const int* in_sizes, int n_in,
                              void* d_out, int out_size, void* d_ws, size_t ws_size,
                              hipStream_t stream) {
  const float* en      = (const float*)d_in[0];
  const float* de      = (const float*)d_in[1];
  const float* gate_w  = (const float*)d_in[2];
  const float* gate_b  = (const float*)d_in[3];
  const float* w1_en   = (const float*)d_in[4];
  const float* b1_en   = (const float*)d_in[5];
  const float* w1_de   = (const float*)d_in[6];
  const float* conv2_k = (const float*)d_in[7];
  const float* conv2_b = (const float*)d_in[8];
  float* ws  = (float*)d_ws;
  float* out = (float*)d_out;

  const unsigned short* bfu = (const unsigned short*)(ws + OFF_WT_EN);
  float* wt_de = ws + OFF_WT_DE;
  float* wc    = ws + OFF_WC;
  float* cesb  = ws + OFF_CES;
  float* cdgb  = ws + OFF_CDG;
  float* gateo = ws + OFF_GATE;
  float* kernb = ws + OFF_KERN;

  hipLaunchKernelGGL(fade_prep,   dim3(322),  dim3(256), 0, stream,
                     w1_en, w1_de, conv2_k, ws, cesb);
  hipLaunchKernelGGL(fade_conv1a, dim3(800),  dim3(256), 0, stream, en, b1_en, bfu, cesb);
  hipLaunchKernelGGL(fade_conv1b, dim3(211),  dim3(256), 0, stream,
                     de, gate_w, gate_b, wt_de, cdgb, gateo);
  hipLaunchKernelGGL(fade_kern,   dim3(800),  dim3(512), 0, stream,
                     wc, cesb, cdgb, conv2_b, kernb);
  hipLaunchKernelGGL(fade_final,  dim3(3200), dim3(256), 0, stream,
                     en, de, kernb, gateo, out);
}

// Round 23
// 109.939 us; speedup vs baseline: 1.4390x; 1.1258x over previous
//
#include <hip/hip_runtime.h>
#include <hip/hip_bf16.h>

// Problem constants
constexpr int BB  = 2;
constexpr int CHN = 256;
constexpr int HH  = 80;
constexpr int WW  = 80;
constexpr int EE  = 64;
constexpr int HO  = 160;
constexpr int WO  = 160;

// Workspace layout (float offsets)
constexpr int OFF_WT_EN = 0;                    // BF bf16 B-fragments (16384 ushort = 8192 floats)
constexpr int OFF_WT_DE = 16384;                // [256][64]  w1_de transposed
constexpr int OFF_WC    = 32768;                // [64][3][3][25] conv2_k transposed
constexpr int OFF_CES   = 47168;                // [B][4][162][162][16] padded+scrambled ce
constexpr int CES_SZ    = 2 * 4 * 162 * 162 * 16;   // 3,359,232
constexpr int OFF_CDG   = OFF_CES + CES_SZ;     // [B][82][82][64] padded cd
constexpr int CDG_SZ    = 2 * 82 * 82 * 64;     // 860,672
constexpr int OFF_GATE  = OFF_CDG + CDG_SZ;     // [B][80][80]
constexpr int OFF_KERN  = OFF_GATE + 2 * 80 * 80;   // [B][80][80][25][4] softmaxed (o-major, q-minor!)

constexpr int NPB = BB * 82 * 82;     // 13448

using bf16x8 = __attribute__((ext_vector_type(8))) short;
using f32x4  = __attribute__((ext_vector_type(4))) float;

// X-macro: apply F to 0..24 (forces compile-time indices -> registers; rule #20)
#define REP25(F) F(0) F(1) F(2) F(3) F(4) F(5) F(6) F(7) F(8) F(9) F(10) F(11) \
                 F(12) F(13) F(14) F(15) F(16) F(17) F(18) F(19) F(20) F(21) F(22) F(23) F(24)

// ---------------------------------------------------------------------------
// prep+border merged (r22 win):
//   - wt_de transpose (conv1b), WC transpose (kern), BF bf16 frags (conv1a)
//   - zero-fill ce_s pad border (yy/xx == 0 or 161)
// ---------------------------------------------------------------------------
__global__ __launch_bounds__(256) void fade_prep(
    const float* __restrict__ w1_en, const float* __restrict__ w1_de,
    const float* __restrict__ conv2_k, float* __restrict__ ws,
    float* __restrict__ ces) {
  int idx = blockIdx.x * 256 + threadIdx.x;
  if (idx < 16384) {
    int c = idx >> 6, e = idx & 63;           // dest = [c][e]
    ws[OFF_WT_DE + idx] = w1_de[e * CHN + c];
    // BF fragment (reuses old wt_en slot, as ushort)
    int j = idx & 7, l = (idx >> 3) & 63, et = (idx >> 9) & 3, ks = idx >> 11;
    int cc = ks * 32 + (l >> 4) * 8 + j;
    int ee = et * 16 + (l & 15);
    unsigned u = __float_as_uint(w1_en[ee * CHN + cc]);
    u = (u + 0x7FFFu + ((u >> 16) & 1u)) >> 16;   // RNE to bf16
    ((unsigned short*)(ws + OFF_WT_EN))[idx] = (unsigned short)u;
  }
  if (idx < 14400) {
    // dest idx = (e*9 + t)*25 + o ; src = conv2_k[(o*64 + e)*9 + t]
    int e = idx / 225, rem = idx % 225, t = rem / 25, o = rem % 25;
    ws[OFF_WC + idx] = conv2_k[(o * EE + e) * 9 + t];
  }
  if (idx < 82432) {
    int e4 = idx & 3;
    int rest = idx >> 2;
    int posb = rest % 644;
    int rest2 = rest / 644;
    int q = rest2 & 3, b = rest2 >> 2;
    int yy, xx;
    if (posb < 162)      { yy = 0;   xx = posb; }
    else if (posb < 324) { yy = 161; xx = posb - 162; }
    else if (posb < 484) { xx = 0;   yy = posb - 324 + 1; }
    else                 { xx = 161; yy = posb - 484 + 1; }
    float4 z = make_float4(0.f, 0.f, 0.f, 0.f);
    *(float4*)(ces + ((((size_t)b * 4 + q) * 162 + yy) * 162 + xx) * 16 + e4 * 4) = z;
  }
}

// ---------------------------------------------------------------------------
// conv1: MERGED conv1a + conv1b (r23: both depend only on prep; merging
// removes one launch gap and lets conv1b's 211 blocks backfill CUs during
// conv1a's ragged tail (800 blocks / 256 CUs = 3.1)).
//   blocks [0,800):    conv1a -- ce = 1x1(en) via bf16 MFMA, double-buffered
//                      LDS staging (r22 win).
//   blocks [800,1011): conv1b -- cd = 1x1(de) + gate, r7 shape (no LDS use).
// ---------------------------------------------------------------------------
__global__ __launch_bounds__(256) void fade_conv1(
    const float* __restrict__ en, const float* __restrict__ b1_en,
    const unsigned short* __restrict__ BFu, float* __restrict__ ces,
    const float* __restrict__ de,
    const float* __restrict__ gate_w, const float* __restrict__ gate_b,
    const float* __restrict__ wt_de,
    float* __restrict__ cdg, float* __restrict__ gateo) {
  __shared__ float buf[2][32][65];
  int bi = blockIdx.x;
  int tid = threadIdx.x;

  if (bi < 800) {
    // ---------------- conv1a path (bf16 MFMA, double-buffered) ----------------
    int b = bi / 400;
    int pos0 = (bi % 400) * 64;       // within batch plane (25600)
    int lane = tid & 63;
    int w = __builtin_amdgcn_readfirstlane(tid >> 6);   // 0..3
    int l15 = lane & 15, lg = lane >> 4;

    const float* ep = en + (size_t)b * CHN * 25600 + pos0;
    const bf16x8* BFF = (const bf16x8*)BFu;

    f32x4 acc0, acc1, acc2, acc3;
    { float bv = b1_en[l15];      acc0 = (f32x4){bv, bv, bv, bv}; }
    { float bv = b1_en[16 + l15]; acc1 = (f32x4){bv, bv, bv, bv}; }
    { float bv = b1_en[32 + l15]; acc2 = (f32x4){bv, bv, bv, bv}; }
    { float bv = b1_en[48 + l15]; acc3 = (f32x4){bv, bv, bv, bv}; }

    int cg = tid >> 6, po = tid & 63;
    // prologue: stage ks=0
#pragma unroll
    for (int i = 0; i < 8; ++i) {
      int c = i * 4 + cg;
      buf[0][c][po] = ep[(size_t)c * 25600 + po];
    }
    __syncthreads();

    for (int ks = 0; ks < 8; ++ks) {
      int p = ks & 1;
      if (ks < 7) {
#pragma unroll
        for (int i = 0; i < 8; ++i) {
          int c = i * 4 + cg;
          buf[p ^ 1][c][po] = ep[(size_t)((ks + 1) * 32 + c) * 25600 + po];
        }
      }
      bf16x8 av;
#define LDA_(j) { unsigned u = __float_as_uint(buf[p][lg * 8 + (j)][w * 16 + l15]); \
      u = (u + 0x7FFFu + ((u >> 16) & 1u)) >> 16; av[(j)] = (short)u; }
      LDA_(0) LDA_(1) LDA_(2) LDA_(3) LDA_(4) LDA_(5) LDA_(6) LDA_(7)
#undef LDA_
      const bf16x8* bp = BFF + ks * 256 + lane;
      bf16x8 b0 = bp[0], b1 = bp[64], b2 = bp[128], b3 = bp[192];
      acc0 = __builtin_amdgcn_mfma_f32_16x16x32_bf16(av, b0, acc0, 0, 0, 0);
      acc1 = __builtin_amdgcn_mfma_f32_16x16x32_bf16(av, b1, acc1, 0, 0, 0);
      acc2 = __builtin_amdgcn_mfma_f32_16x16x32_bf16(av, b2, acc2, 0, 0, 0);
      acc3 = __builtin_amdgcn_mfma_f32_16x16x32_bf16(av, b3, acc3, 0, 0, 0);
      __syncthreads();
    }

    // scrambled write: ce_s[b][q][yy][xx][e'] = acc_full[4e'+q]; e = 4e'+q
    constexpr size_t QSTR = (size_t)162 * 162 * 16;
    float* cb = ces + (size_t)b * 4 * QSTR;
    int pbase = pos0 + w * 16 + lg * 4;
    int q = l15 & 3;
#define WR_(r) { int p2 = pbase + (r); int y = p2 / 160, x = p2 - y * 160; \
      size_t sb = (size_t)q * QSTR + (size_t)((y + 1) * 162 + (x + 1)) * 16 + (l15 >> 2); \
      cb[sb +  0] = acc0[(r)]; \
      cb[sb +  4] = acc1[(r)]; \
      cb[sb +  8] = acc2[(r)]; \
      cb[sb + 12] = acc3[(r)]; }
    WR_(0) WR_(1) WR_(2) WR_(3)
#undef WR_
  } else {
    // ---------------- conv1b path (VALU, r7 shape) ----------------
    int id64 = tid & 63;
    int eg = __builtin_amdgcn_readfirstlane(tid >> 6);   // 0..3
    int pos = (bi - 800) * 64 + id64;
    if (pos >= NPB) return;

    int b = pos / (82 * 82), r = pos % (82 * 82);
    int yy = r / 82, xx = r % 82;
    int y = yy - 1, x = xx - 1;
    float* cop = cdg + (((size_t)b * 82 + yy) * 82 + xx) * 64 + eg * 16;
    if (y >= 0 && y < HH && x >= 0 && x < WW) {
      float acc[16];
#pragma unroll
      for (int e = 0; e < 16; ++e) acc[e] = 0.f;
      float g = gate_b[0];
      const float* dp = de + (size_t)b * CHN * HH * WW + (size_t)y * WW + x;
      float cur[8];
#pragma unroll
      for (int j = 0; j < 8; ++j) cur[j] = dp[(size_t)j * HH * WW];
      for (int c0 = 0; c0 < CHN; c0 += 8) {
        float nxt[8];
        if (c0 + 8 < CHN) {
#pragma unroll
          for (int j = 0; j < 8; ++j) nxt[j] = dp[(size_t)(c0 + 8 + j) * HH * WW];
        }
#pragma unroll
        for (int j = 0; j < 8; ++j) {
          float v = cur[j];
          const float* wr = wt_de + (c0 + j) * 64 + eg * 16;
#pragma unroll
          for (int e = 0; e < 16; ++e) acc[e] = fmaf(v, wr[e], acc[e]);
          g = fmaf(v, gate_w[c0 + j], g);
        }
        if (c0 + 8 < CHN) {
#pragma unroll
          for (int j = 0; j < 8; ++j) cur[j] = nxt[j];
        }
      }
#pragma unroll
      for (int m = 0; m < 4; ++m) {
        float4 v = make_float4(acc[4 * m], acc[4 * m + 1], acc[4 * m + 2], acc[4 * m + 3]);
        *(float4*)(cop + m * 4) = v;
      }
      if (eg == 0)
        gateo[((size_t)b * 80 + y) * 80 + x] = 1.f / (1.f + __expf(-g));
    } else {
      float4 z = make_float4(0.f, 0.f, 0.f, 0.f);
#pragma unroll
      for (int m = 0; m < 4; ++m) *(float4*)(cop + m * 4) = z;
    }
  }
}

// ---------------------------------------------------------------------------
// kern: MERGED k_de+k_en tap loop (r13 win) + 2-stage pipeline (r21 win).
// Runtime d-loop retained; two-phase LDS reduction (32KB) retained.
// ---------------------------------------------------------------------------
__global__ __launch_bounds__(512) void fade_kern(
    const float* __restrict__ WC, const float* __restrict__ CES,
    const float* __restrict__ CDG, const float* __restrict__ conv2_b,
    float* __restrict__ KERN) {
  __shared__ float part[64 * 101];   // [row][(wv&3)*25+o], stride 101 (conflict-free)
  __shared__ float score[64 * 27];
  int bi = blockIdx.x;
  int b = bi / 400, t = bi % 400;
  int th0 = (t / 20) * 4, tw0 = (t % 20) * 4;
  int tid = threadIdx.x;
  int lane = tid & 63;
  int wv = __builtin_amdgcn_readfirstlane(tid >> 6);   // 0..7 K-slice
  int cell = lane >> 2, q = lane & 3;
  int h = th0 + (cell >> 2), w = tw0 + (cell & 3);

#define KDECL_(i) float a##i = 0.f;
  REP25(KDECL_)

#define KCH(val, base) { const float vv = (val); const float* wb = (base); \
    REP25(KFMA_) }
#define KFMA_(i) a##i = fmaf(vv, wb[(i)], a##i);

  // merged k_de + k_en over 9 taps; channels 8wv..8wv+8; 2-stage pipeline
  {
    int g = wv >> 1;
    const int pt = (g < 2) ? 1 : 0;
    const int pl = (g & 1) ? 0 : 1;
    const int eb = 8 * (wv & 1);
    const float* cpd_base = CDG + (((size_t)b * 82 + h) * 82 + w) * 64 + 8 * wv;
    const float* cpe_base = CES + ((((size_t)b * 4 + q) * 162 + (2 * h + 1 - pt)) * 162 +
                                   (2 * w + 1 - pl)) * 16 + eb;
    float4 u0 = *(const float4*)(cpd_base);
    float4 u1 = *(const float4*)(cpd_base + 4);
    float4 v0 = *(const float4*)(cpe_base);
    float4 v1 = *(const float4*)(cpe_base + 4);
    for (int d = 0; d < 9; ++d) {
      float4 nu0, nu1, nv0, nv1;
      if (d < 8) {
        int dn = d + 1;
        int di = dn / 3, dj = dn - 3 * di;       // wave-uniform SALU
        const float* cpd = cpd_base + (di * 82 + dj) * 64;
        const float* cpe = cpe_base + (di * 162 + dj) * 16;
        nu0 = *(const float4*)(cpd);
        nu1 = *(const float4*)(cpd + 4);
        nv0 = *(const float4*)(cpe);
        nv1 = *(const float4*)(cpe + 4);
      }
      const float* wt = WC + (8 * wv * 9 + d) * 25;
      KCH(u0.x + v0.x, wt)         KCH(u0.y + v0.y, wt + 225)
      KCH(u0.z + v0.z, wt + 450)   KCH(u0.w + v0.w, wt + 675)
      KCH(u1.x + v1.x, wt + 900)   KCH(u1.y + v1.y, wt + 1125)
      KCH(u1.z + v1.z, wt + 1350)  KCH(u1.w + v1.w, wt + 1575)
      if (d < 8) { u0 = nu0; u1 = nu1; v0 = nv0; v1 = nv1; }
    }
  }

  {
    int pbase = lane * 101 + (wv & 3) * 25;
    if (wv < 4) {
#define KST_(i) part[pbase + (i)] = a##i;
      REP25(KST_)
    }
    __syncthreads();
    if (wv >= 4) {
#define KAD_(i) part[pbase + (i)] += a##i;
      REP25(KAD_)
    }
  }
  __syncthreads();

  {
    int row = tid & 63, sub = tid >> 6;
    int nO = (sub == 7) ? 4 : 3;
    for (int m = 0; m < nO; ++m) {
      int o = sub * 3 + m;
      float s = 0.f;
#pragma unroll
      for (int w4 = 0; w4 < 4; ++w4) s += part[row * 101 + w4 * 25 + o];
      score[row * 27 + o] = s + 2.f * conv2_b[o];   // bias in BOTH k_en and k_de
    }
  }
  __syncthreads();

  if (tid < 64) {
    int sbase = tid * 27;
#define SLD_(i) float s##i = score[sbase + (i)];
    REP25(SLD_)
    float mx = s0;
#define SMX_(i) mx = fmaxf(mx, s##i);
    REP25(SMX_)
    float sum = 0.f;
#define SEX_(i) s##i = __expf(s##i - mx); sum += s##i;
    REP25(SEX_)
    float inv = 1.f / sum;
    int cl = tid >> 2, qq = tid & 3;
    int hh = th0 + (cl >> 2), ww2 = tw0 + (cl & 3);
    float* kp = KERN + (size_t)(b * 6400 + hh * 80 + ww2) * 100;
#define SWR_(i) kp[(i) * 4 + qq] = s##i * inv;
    REP25(SWR_)
  }
}

// ---------------------------------------------------------------------------
// final: CARAFE + gate blend, r18 structure (LDS kern staging).
// ---------------------------------------------------------------------------
__global__ __launch_bounds__(256) void fade_final(
    const float* __restrict__ en, const float* __restrict__ de,
    const float* __restrict__ KERN, const float* __restrict__ GATE,
    float* __restrict__ out) {
  __shared__ float sde[32 * 105];    // 32 channels x (8 rows x 13 cols pad)
  __shared__ float4 kled[25][33];    // [o][cell], pad 33 vs write conflicts
  int bi = blockIdx.x;
  int b = bi / 1600, r = bi % 1600;
  int t = r >> 3, cc = r & 7;
  int th0 = (t / 10) * 4, tw0 = (t % 10) * 8;
  int tid = threadIdx.x;
  int sg = tid >> 5, cell = tid & 31;
  int chh = cell >> 3, cw = cell & 7;
  int h = th0 + chh, w = tw0 + cw;

  // stage de: channels cc*32 .. +32, rows th0-2..+5, cols tw0-2..+9
  for (int kk = tid; kk < 3072; kk += 256) {
    int ci = kk / 96, rem = kk % 96, rr = rem / 12, c2 = rem % 12;
    int dr = th0 - 2 + rr, dc = tw0 - 2 + c2;
    float v = 0.f;
    if (dr >= 0 && dr < HH && dc >= 0 && dc < WW)
      v = de[((size_t)(b * CHN + cc * 32 + ci) * HH + dr) * WW + dc];
    sde[ci * 105 + rr * 13 + c2] = v;
  }
  // stage kern: 800 float4 (32 cells x 25 o), coalesced (o fastest)
  for (int kk = tid; kk < 800; kk += 256) {
    int cl2 = kk / 25, o = kk % 25;
    int hc = th0 + (cl2 >> 3), wc = tw0 + (cl2 & 7);
    kled[o][cl2] = *((const float4*)(KERN + (size_t)(b * 6400 + hc * 80 + wc) * 100) + o);
  }
  __syncthreads();

  float gv = GATE[((size_t)b * 80 + h) * 80 + w];
  float gv1 = 1.f - gv;

#pragma unroll
  for (int j = 0; j < 4; ++j) {
    int c = cc * 32 + sg * 4 + j;
    int sbase2 = (sg * 4 + j) * 105 + chh * 13 + cw;
#define FWD_(o) float w##o = sde[sbase2 + ((o) / 5) * 13 + ((o) % 5)];
    REP25(FWD_)
    float s00 = 0.f, s01 = 0.f, s10 = 0.f, s11 = 0.f;
#define FCF_(o) { float4 kv = kled[(o)][cell]; \
                  s00 = fmaf(w##o, kv.x, s00); s01 = fmaf(w##o, kv.y, s01); \
                  s10 = fmaf(w##o, kv.z, s10); s11 = fmaf(w##o, kv.w, s11); }
    REP25(FCF_)

    const float* ep = en + ((size_t)(b * CHN + c) * HO + 2 * h) * WO + 2 * w;
    float* op = out + ((size_t)(b * CHN + c) * HO + 2 * h) * WO + 2 * w;
    float2 e0 = *(const float2*)(ep);
    float2 e1 = *(const float2*)(ep + WO);
    float2 r0, r1;
    r0.x = fmaf(gv, e0.x, gv1 * s00);
    r0.y = fmaf(gv, e0.y, gv1 * s01);
    r1.x = fmaf(gv, e1.x, gv1 * s10);
    r1.y = fmaf(gv, e1.y, gv1 * s11);
    *(float2*)(op) = r0;
    *(float2*)(op + WO) = r1;
  }
}

// ---------------------------------------------------------------------------
extern "C" void kernel_launch(void* const* d_in, const int* in_sizes, int n_in,
                              void* d_out, int out_size, void* d_ws, size_t ws_size,
                              hipStream_t stream) {
  const float* en      = (const float*)d_in[0];
  const float* de      = (const float*)d_in[1];
  const float* gate_w  = (const float*)d_in[2];
  const float* gate_b  = (const float*)d_in[3];
  const float* w1_en   = (const float*)d_in[4];
  const float* b1_en   = (const float*)d_in[5];
  const float* w1_de   = (const float*)d_in[6];
  const float* conv2_k = (const float*)d_in[7];
  const float* conv2_b = (const float*)d_in[8];
  float* ws  = (float*)d_ws;
  float* out = (float*)d_out;

  const unsigned short* bfu = (const unsigned short*)(ws + OFF_WT_EN);
  float* wt_de = ws + OFF_WT_DE;
  float* wc    = ws + OFF_WC;
  float* cesb  = ws + OFF_CES;
  float* cdgb  = ws + OFF_CDG;
  float* gateo = ws + OFF_GATE;
  float* kernb = ws + OFF_KERN;

  hipLaunchKernelGGL(fade_prep,   dim3(322),  dim3(256), 0, stream,
                     w1_en, w1_de, conv2_k, ws, cesb);
  hipLaunchKernelGGL(fade_conv1,  dim3(1011), dim3(256), 0, stream,
                     en, b1_en, bfu, cesb, de, gate_w, gate_b, wt_de, cdgb, gateo);
  hipLaunchKernelGGL(fade_kern,   dim3(800),  dim3(512), 0, stream,
                     wc, cesb, cdgb, conv2_b, kernb);
  hipLaunchKernelGGL(fade_final,  dim3(3200), dim3(256), 0, stream,
                     en, de, kernb, gateo, out);
}

// Round 24
// 92.449 us; speedup vs baseline: 1.7112x; 1.1892x over previous
//
#include <hip/hip_runtime.h>
#include <hip/hip_bf16.h>

// Problem constants
constexpr int BB  = 2;
constexpr int CHN = 256;
constexpr int HH  = 80;
constexpr int WW  = 80;
constexpr int EE  = 64;
constexpr int HO  = 160;
constexpr int WO  = 160;

// Workspace layout (float offsets)
constexpr int OFF_WT_EN = 0;                    // BF bf16 B-frags of w1_en (16384 ushort)
constexpr int OFF_WT_DE = 16384;                // BF_DE bf16 B-frags of w1_de (16384 ushort) + BG gate frags (4096 ushort)
constexpr int OFF_WC    = 32768;                // [64][3][3][25] conv2_k transposed
constexpr int OFF_CES   = 47168;                // [B][4][162][162][16] padded+scrambled ce
constexpr int CES_SZ    = 2 * 4 * 162 * 162 * 16;   // 3,359,232
constexpr int OFF_CDG   = OFF_CES + CES_SZ;     // [B][82][82][64] padded cd
constexpr int CDG_SZ    = 2 * 82 * 82 * 64;     // 860,672
constexpr int OFF_GATE  = OFF_CDG + CDG_SZ;     // [B][80][80]
constexpr int OFF_KERN  = OFF_GATE + 2 * 80 * 80;   // [B][80][80][25][4] softmaxed (o-major, q-minor!)

using bf16x8 = __attribute__((ext_vector_type(8))) short;
using f32x4  = __attribute__((ext_vector_type(4))) float;

// X-macro: apply F to 0..24 (forces compile-time indices -> registers; rule #20)
#define REP25(F) F(0) F(1) F(2) F(3) F(4) F(5) F(6) F(7) F(8) F(9) F(10) F(11) \
                 F(12) F(13) F(14) F(15) F(16) F(17) F(18) F(19) F(20) F(21) F(22) F(23) F(24)

// ---------------------------------------------------------------------------
// prep (merged, r22/r24): all weight transforms + both pad-border zero-fills.
//  - BF  = bf16 MFMA B-frags of w1_en  -> OFF_WT_EN (ushort)
//  - BF_DE = same for w1_de            -> OFF_WT_DE (ushort)
//  - BG  = gate_w in col 0, 0 else     -> OFF_WT_DE + 16384 ushorts
//  - WC transpose (kern)
//  - ce_s pad ring zero-fill (82432 float4)
//  - cdg pad ring zero-fill (10368 float4)  [r24: conv1b path is now MFMA
//    interior-only, so its ring writes moved here]
// ---------------------------------------------------------------------------
__global__ __launch_bounds__(256) void fade_prep(
    const float* __restrict__ w1_en, const float* __restrict__ w1_de,
    const float* __restrict__ gate_w, const float* __restrict__ conv2_k,
    float* __restrict__ ws, float* __restrict__ ces, float* __restrict__ cdg) {
  int idx = blockIdx.x * 256 + threadIdx.x;
  if (idx < 16384) {
    int j = idx & 7, l = (idx >> 3) & 63, et = (idx >> 9) & 3, ks = idx >> 11;
    int cc = ks * 32 + (l >> 4) * 8 + j;
    int ee = et * 16 + (l & 15);
    unsigned u = __float_as_uint(w1_en[ee * CHN + cc]);
    u = (u + 0x7FFFu + ((u >> 16) & 1u)) >> 16;   // RNE to bf16
    ((unsigned short*)(ws + OFF_WT_EN))[idx] = (unsigned short)u;
    unsigned v = __float_as_uint(w1_de[ee * CHN + cc]);
    v = (v + 0x7FFFu + ((v >> 16) & 1u)) >> 16;
    ((unsigned short*)(ws + OFF_WT_DE))[idx] = (unsigned short)v;
  }
  if (idx < 4096) {
    // BG: gate fragment, col 0 = gate_w, other cols 0. ks = idx>>9 (0..7)
    int j = idx & 7, l = (idx >> 3) & 63, ks = idx >> 9;
    int cc = ks * 32 + (l >> 4) * 8 + j;
    unsigned short r = 0;
    if ((l & 15) == 0) {
      unsigned u = __float_as_uint(gate_w[cc]);
      u = (u + 0x7FFFu + ((u >> 16) & 1u)) >> 16;
      r = (unsigned short)u;
    }
    ((unsigned short*)(ws + OFF_WT_DE))[16384 + idx] = r;
  }
  if (idx < 14400) {
    // dest idx = (e*9 + t)*25 + o ; src = conv2_k[(o*64 + e)*9 + t]
    int e = idx / 225, rem = idx % 225, t = rem / 25, o = rem % 25;
    ws[OFF_WC + idx] = conv2_k[(o * EE + e) * 9 + t];
  }
  if (idx < 82432) {
    int e4 = idx & 3;
    int rest = idx >> 2;
    int posb = rest % 644;
    int rest2 = rest / 644;
    int q = rest2 & 3, b = rest2 >> 2;
    int yy, xx;
    if (posb < 162)      { yy = 0;   xx = posb; }
    else if (posb < 324) { yy = 161; xx = posb - 162; }
    else if (posb < 484) { xx = 0;   yy = posb - 324 + 1; }
    else                 { xx = 161; yy = posb - 484 + 1; }
    float4 z = make_float4(0.f, 0.f, 0.f, 0.f);
    *(float4*)(ces + ((((size_t)b * 4 + q) * 162 + yy) * 162 + xx) * 16 + e4 * 4) = z;
  }
  if (idx < 10368) {
    // cdg pad ring: 324 cells/batch x 16 float4
    int e4 = idx & 15;
    int rest = idx >> 4;
    int cell = rest % 324, b = rest / 324;
    int yy, xx;
    if (cell < 82)       { yy = 0;  xx = cell; }
    else if (cell < 164) { yy = 81; xx = cell - 82; }
    else if (cell < 244) { xx = 0;  yy = cell - 164 + 1; }
    else                 { xx = 81; yy = cell - 244 + 1; }
    float4 z = make_float4(0.f, 0.f, 0.f, 0.f);
    *(float4*)(cdg + (((size_t)b * 82 + yy) * 82 + xx) * 64 + e4 * 4) = z;
  }
}

// ---------------------------------------------------------------------------
// conv1 (r24): BOTH 1x1 convs via bf16 MFMA, double-buffered LDS staging.
//   blocks [0,800):    ce = 1x1(en) -> scrambled ce_s interior
//   blocks [800,1000): cd = 1x1(de) -> cdg interior, + gate via a 5th MFMA
//                      (B-frag = gate_w in col 0; lanes l15==0 hold the dot)
// r23 profile: merged kernel 40us, VALU 13%, Mfma 1.4% -- the 211-block
// scalar conv1b path was the latency-bound pole. Now 1000 uniform MFMA blocks.
// ---------------------------------------------------------------------------
__global__ __launch_bounds__(256) void fade_conv1(
    const float* __restrict__ en, const float* __restrict__ b1_en,
    const unsigned short* __restrict__ BFu, float* __restrict__ ces,
    const float* __restrict__ de, const float* __restrict__ gate_b,
    const unsigned short* __restrict__ BFDu,
    float* __restrict__ cdg, float* __restrict__ gateo) {
  __shared__ float buf[2][32][65];
  int bi = blockIdx.x;
  int tid = threadIdx.x;
  int lane = tid & 63;
  int w = __builtin_amdgcn_readfirstlane(tid >> 6);   // 0..3
  int l15 = lane & 15, lg = lane >> 4;
  int cg = tid >> 6, po = tid & 63;

  if (bi < 800) {
    // ---------------- en path ----------------
    int b = bi / 400;
    int pos0 = (bi % 400) * 64;       // within batch plane (25600)
    const float* ep = en + (size_t)b * CHN * 25600 + pos0;
    const bf16x8* BFF = (const bf16x8*)BFu;

    f32x4 acc0, acc1, acc2, acc3;
    { float bv = b1_en[l15];      acc0 = (f32x4){bv, bv, bv, bv}; }
    { float bv = b1_en[16 + l15]; acc1 = (f32x4){bv, bv, bv, bv}; }
    { float bv = b1_en[32 + l15]; acc2 = (f32x4){bv, bv, bv, bv}; }
    { float bv = b1_en[48 + l15]; acc3 = (f32x4){bv, bv, bv, bv}; }

#pragma unroll
    for (int i = 0; i < 8; ++i) {
      int c = i * 4 + cg;
      buf[0][c][po] = ep[(size_t)c * 25600 + po];
    }
    __syncthreads();

    for (int ks = 0; ks < 8; ++ks) {
      int p = ks & 1;
      if (ks < 7) {
#pragma unroll
        for (int i = 0; i < 8; ++i) {
          int c = i * 4 + cg;
          buf[p ^ 1][c][po] = ep[(size_t)((ks + 1) * 32 + c) * 25600 + po];
        }
      }
      bf16x8 av;
#define LDA_(j) { unsigned u = __float_as_uint(buf[p][lg * 8 + (j)][w * 16 + l15]); \
      u = (u + 0x7FFFu + ((u >> 16) & 1u)) >> 16; av[(j)] = (short)u; }
      LDA_(0) LDA_(1) LDA_(2) LDA_(3) LDA_(4) LDA_(5) LDA_(6) LDA_(7)
#undef LDA_
      const bf16x8* bp = BFF + ks * 256 + lane;
      bf16x8 b0 = bp[0], b1 = bp[64], b2 = bp[128], b3 = bp[192];
      acc0 = __builtin_amdgcn_mfma_f32_16x16x32_bf16(av, b0, acc0, 0, 0, 0);
      acc1 = __builtin_amdgcn_mfma_f32_16x16x32_bf16(av, b1, acc1, 0, 0, 0);
      acc2 = __builtin_amdgcn_mfma_f32_16x16x32_bf16(av, b2, acc2, 0, 0, 0);
      acc3 = __builtin_amdgcn_mfma_f32_16x16x32_bf16(av, b3, acc3, 0, 0, 0);
      __syncthreads();
    }

    // scrambled write: ce_s[b][q][yy][xx][e'] = acc_full[4e'+q]; e = 4e'+q
    constexpr size_t QSTR = (size_t)162 * 162 * 16;
    float* cb = ces + (size_t)b * 4 * QSTR;
    int pbase = pos0 + w * 16 + lg * 4;
    int q = l15 & 3;
#define WR_(r) { int p2 = pbase + (r); int y = p2 / 160, x = p2 - y * 160; \
      size_t sb = (size_t)q * QSTR + (size_t)((y + 1) * 162 + (x + 1)) * 16 + (l15 >> 2); \
      cb[sb +  0] = acc0[(r)]; \
      cb[sb +  4] = acc1[(r)]; \
      cb[sb +  8] = acc2[(r)]; \
      cb[sb + 12] = acc3[(r)]; }
    WR_(0) WR_(1) WR_(2) WR_(3)
#undef WR_
  } else {
    // ---------------- de path (MFMA + gate column) ----------------
    int bj = bi - 800;
    int b = bj / 100;
    int pos0 = (bj % 100) * 64;       // within de plane (6400)
    const float* dp = de + (size_t)b * CHN * 6400 + pos0;
    const bf16x8* BFD = (const bf16x8*)BFDu;
    const bf16x8* BG  = (const bf16x8*)(BFDu + 16384);

    f32x4 acc0 = {0.f, 0.f, 0.f, 0.f}, acc1 = acc0, acc2 = acc0, acc3 = acc0;
    f32x4 accg;
    { float gb = gate_b[0]; accg = (f32x4){gb, gb, gb, gb}; }

#pragma unroll
    for (int i = 0; i < 8; ++i) {
      int c = i * 4 + cg;
      buf[0][c][po] = dp[(size_t)c * 6400 + po];
    }
    __syncthreads();

    for (int ks = 0; ks < 8; ++ks) {
      int p = ks & 1;
      if (ks < 7) {
#pragma unroll
        for (int i = 0; i < 8; ++i) {
          int c = i * 4 + cg;
          buf[p ^ 1][c][po] = dp[(size_t)((ks + 1) * 32 + c) * 6400 + po];
        }
      }
      bf16x8 av;
#define LDB_(j) { unsigned u = __float_as_uint(buf[p][lg * 8 + (j)][w * 16 + l15]); \
      u = (u + 0x7FFFu + ((u >> 16) & 1u)) >> 16; av[(j)] = (short)u; }
      LDB_(0) LDB_(1) LDB_(2) LDB_(3) LDB_(4) LDB_(5) LDB_(6) LDB_(7)
#undef LDB_
      const bf16x8* bp = BFD + ks * 256 + lane;
      bf16x8 b0 = bp[0], b1 = bp[64], b2 = bp[128], b3 = bp[192];
      bf16x8 bg = BG[ks * 64 + lane];
      acc0 = __builtin_amdgcn_mfma_f32_16x16x32_bf16(av, b0, acc0, 0, 0, 0);
      acc1 = __builtin_amdgcn_mfma_f32_16x16x32_bf16(av, b1, acc1, 0, 0, 0);
      acc2 = __builtin_amdgcn_mfma_f32_16x16x32_bf16(av, b2, acc2, 0, 0, 0);
      acc3 = __builtin_amdgcn_mfma_f32_16x16x32_bf16(av, b3, acc3, 0, 0, 0);
      accg = __builtin_amdgcn_mfma_f32_16x16x32_bf16(av, bg, accg, 0, 0, 0);
      __syncthreads();
    }

    // cdg interior write: cdg[b][y+1][x+1][e], e = 16*chunk + l15
    float* cdb = cdg + (size_t)b * 82 * 82 * 64;
    int pbase = pos0 + w * 16 + lg * 4;
#define WRD_(r) { int p2 = pbase + (r); int y = p2 / 80, x = p2 - y * 80; \
      size_t sb = (size_t)((y + 1) * 82 + (x + 1)) * 64 + l15; \
      cdb[sb +  0] = acc0[(r)]; \
      cdb[sb + 16] = acc1[(r)]; \
      cdb[sb + 32] = acc2[(r)]; \
      cdb[sb + 48] = acc3[(r)]; \
      if (l15 == 0) gateo[(size_t)b * 6400 + p2] = 1.f / (1.f + __expf(-accg[(r)])); }
    WRD_(0) WRD_(1) WRD_(2) WRD_(3)
#undef WRD_
  }
}

// ---------------------------------------------------------------------------
// kern: MERGED k_de+k_en tap loop (r13 win) + 2-stage pipeline (r21 win).
// Runtime d-loop retained; two-phase LDS reduction (32KB) retained.
// ---------------------------------------------------------------------------
__global__ __launch_bounds__(512) void fade_kern(
    const float* __restrict__ WC, const float* __restrict__ CES,
    const float* __restrict__ CDG, const float* __restrict__ conv2_b,
    float* __restrict__ KERN) {
  __shared__ float part[64 * 101];   // [row][(wv&3)*25+o], stride 101 (conflict-free)
  __shared__ float score[64 * 27];
  int bi = blockIdx.x;
  int b = bi / 400, t = bi % 400;
  int th0 = (t / 20) * 4, tw0 = (t % 20) * 4;
  int tid = threadIdx.x;
  int lane = tid & 63;
  int wv = __builtin_amdgcn_readfirstlane(tid >> 6);   // 0..7 K-slice
  int cell = lane >> 2, q = lane & 3;
  int h = th0 + (cell >> 2), w = tw0 + (cell & 3);

#define KDECL_(i) float a##i = 0.f;
  REP25(KDECL_)

#define KCH(val, base) { const float vv = (val); const float* wb = (base); \
    REP25(KFMA_) }
#define KFMA_(i) a##i = fmaf(vv, wb[(i)], a##i);

  // merged k_de + k_en over 9 taps; channels 8wv..8wv+8; 2-stage pipeline
  {
    int g = wv >> 1;
    const int pt = (g < 2) ? 1 : 0;
    const int pl = (g & 1) ? 0 : 1;
    const int eb = 8 * (wv & 1);
    const float* cpd_base = CDG + (((size_t)b * 82 + h) * 82 + w) * 64 + 8 * wv;
    const float* cpe_base = CES + ((((size_t)b * 4 + q) * 162 + (2 * h + 1 - pt)) * 162 +
                                   (2 * w + 1 - pl)) * 16 + eb;
    float4 u0 = *(const float4*)(cpd_base);
    float4 u1 = *(const float4*)(cpd_base + 4);
    float4 v0 = *(const float4*)(cpe_base);
    float4 v1 = *(const float4*)(cpe_base + 4);
    for (int d = 0; d < 9; ++d) {
      float4 nu0, nu1, nv0, nv1;
      if (d < 8) {
        int dn = d + 1;
        int di = dn / 3, dj = dn - 3 * di;       // wave-uniform SALU
        const float* cpd = cpd_base + (di * 82 + dj) * 64;
        const float* cpe = cpe_base + (di * 162 + dj) * 16;
        nu0 = *(const float4*)(cpd);
        nu1 = *(const float4*)(cpd + 4);
        nv0 = *(const float4*)(cpe);
        nv1 = *(const float4*)(cpe + 4);
      }
      const float* wt = WC + (8 * wv * 9 + d) * 25;
      KCH(u0.x + v0.x, wt)         KCH(u0.y + v0.y, wt + 225)
      KCH(u0.z + v0.z, wt + 450)   KCH(u0.w + v0.w, wt + 675)
      KCH(u1.x + v1.x, wt + 900)   KCH(u1.y + v1.y, wt + 1125)
      KCH(u1.z + v1.z, wt + 1350)  KCH(u1.w + v1.w, wt + 1575)
      if (d < 8) { u0 = nu0; u1 = nu1; v0 = nv0; v1 = nv1; }
    }
  }

  {
    int pbase = lane * 101 + (wv & 3) * 25;
    if (wv < 4) {
#define KST_(i) part[pbase + (i)] = a##i;
      REP25(KST_)
    }
    __syncthreads();
    if (wv >= 4) {
#define KAD_(i) part[pbase + (i)] += a##i;
      REP25(KAD_)
    }
  }
  __syncthreads();

  {
    int row = tid & 63, sub = tid >> 6;
    int nO = (sub == 7) ? 4 : 3;
    for (int m = 0; m < nO; ++m) {
      int o = sub * 3 + m;
      float s = 0.f;
#pragma unroll
      for (int w4 = 0; w4 < 4; ++w4) s += part[row * 101 + w4 * 25 + o];
      score[row * 27 + o] = s + 2.f * conv2_b[o];   // bias in BOTH k_en and k_de
    }
  }
  __syncthreads();

  if (tid < 64) {
    int sbase = tid * 27;
#define SLD_(i) float s##i = score[sbase + (i)];
    REP25(SLD_)
    float mx = s0;
#define SMX_(i) mx = fmaxf(mx, s##i);
    REP25(SMX_)
    float sum = 0.f;
#define SEX_(i) s##i = __expf(s##i - mx); sum += s##i;
    REP25(SEX_)
    float inv = 1.f / sum;
    int cl = tid >> 2, qq = tid & 3;
    int hh = th0 + (cl >> 2), ww2 = tw0 + (cl & 3);
    float* kp = KERN + (size_t)(b * 6400 + hh * 80 + ww2) * 100;
#define SWR_(i) kp[(i) * 4 + qq] = s##i * inv;
    REP25(SWR_)
  }
}

// ---------------------------------------------------------------------------
// final: CARAFE + gate blend, r18 structure (LDS kern staging).
// ---------------------------------------------------------------------------
__global__ __launch_bounds__(256) void fade_final(
    const float* __restrict__ en, const float* __restrict__ de,
    const float* __restrict__ KERN, const float* __restrict__ GATE,
    float* __restrict__ out) {
  __shared__ float sde[32 * 105];    // 32 channels x (8 rows x 13 cols pad)
  __shared__ float4 kled[25][33];    // [o][cell], pad 33 vs write conflicts
  int bi = blockIdx.x;
  int b = bi / 1600, r = bi % 1600;
  int t = r >> 3, cc = r & 7;
  int th0 = (t / 10) * 4, tw0 = (t % 10) * 8;
  int tid = threadIdx.x;
  int sg = tid >> 5, cell = tid & 31;
  int chh = cell >> 3, cw = cell & 7;
  int h = th0 + chh, w = tw0 + cw;

  // stage de: channels cc*32 .. +32, rows th0-2..+5, cols tw0-2..+9
  for (int kk = tid; kk < 3072; kk += 256) {
    int ci = kk / 96, rem = kk % 96, rr = rem / 12, c2 = rem % 12;
    int dr = th0 - 2 + rr, dc = tw0 - 2 + c2;
    float v = 0.f;
    if (dr >= 0 && dr < HH && dc >= 0 && dc < WW)
      v = de[((size_t)(b * CHN + cc * 32 + ci) * HH + dr) * WW + dc];
    sde[ci * 105 + rr * 13 + c2] = v;
  }
  // stage kern: 800 float4 (32 cells x 25 o), coalesced (o fastest)
  for (int kk = tid; kk < 800; kk += 256) {
    int cl2 = kk / 25, o = kk % 25;
    int hc = th0 + (cl2 >> 3), wc = tw0 + (cl2 & 7);
    kled[o][cl2] = *((const float4*)(KERN + (size_t)(b * 6400 + hc * 80 + wc) * 100) + o);
  }
  __syncthreads();

  float gv = GATE[((size_t)b * 80 + h) * 80 + w];
  float gv1 = 1.f - gv;

#pragma unroll
  for (int j = 0; j < 4; ++j) {
    int c = cc * 32 + sg * 4 + j;
    int sbase2 = (sg * 4 + j) * 105 + chh * 13 + cw;
#define FWD_(o) float w##o = sde[sbase2 + ((o) / 5) * 13 + ((o) % 5)];
    REP25(FWD_)
    float s00 = 0.f, s01 = 0.f, s10 = 0.f, s11 = 0.f;
#define FCF_(o) { float4 kv = kled[(o)][cell]; \
                  s00 = fmaf(w##o, kv.x, s00); s01 = fmaf(w##o, kv.y, s01); \
                  s10 = fmaf(w##o, kv.z, s10); s11 = fmaf(w##o, kv.w, s11); }
    REP25(FCF_)

    const float* ep = en + ((size_t)(b * CHN + c) * HO + 2 * h) * WO + 2 * w;
    float* op = out + ((size_t)(b * CHN + c) * HO + 2 * h) * WO + 2 * w;
    float2 e0 = *(const float2*)(ep);
    float2 e1 = *(const float2*)(ep + WO);
    float2 r0, r1;
    r0.x = fmaf(gv, e0.x, gv1 * s00);
    r0.y = fmaf(gv, e0.y, gv1 * s01);
    r1.x = fmaf(gv, e1.x, gv1 * s10);
    r1.y = fmaf(gv, e1.y, gv1 * s11);
    *(float2*)(op) = r0;
    *(float2*)(op + WO) = r1;
  }
}

// ---------------------------------------------------------------------------
extern "C" void kernel_launch(void* const* d_in, const int* in_sizes, int n_in,
                              void* d_out, int out_size, void* d_ws, size_t ws_size,
                              hipStream_t stream) {
  const float* en      = (const float*)d_in[0];
  const float* de      = (const float*)d_in[1];
  const float* gate_w  = (const float*)d_in[2];
  const float* gate_b  = (const float*)d_in[3];
  const float* w1_en   = (const float*)d_in[4];
  const float* b1_en   = (const float*)d_in[5];
  const float* w1_de   = (const float*)d_in[6];
  const float* conv2_k = (const float*)d_in[7];
  const float* conv2_b = (const float*)d_in[8];
  float* ws  = (float*)d_ws;
  float* out = (float*)d_out;

  const unsigned short* bfu  = (const unsigned short*)(ws + OFF_WT_EN);
  const unsigned short* bfdu = (const unsigned short*)(ws + OFF_WT_DE);
  float* wc    = ws + OFF_WC;
  float* cesb  = ws + OFF_CES;
  float* cdgb  = ws + OFF_CDG;
  float* gateo = ws + OFF_GATE;
  float* kernb = ws + OFF_KERN;

  hipLaunchKernelGGL(fade_prep,   dim3(322),  dim3(256), 0, stream,
                     w1_en, w1_de, gate_w, conv2_k, ws, cesb, cdgb);
  hipLaunchKernelGGL(fade_conv1,  dim3(1000), dim3(256), 0, stream,
                     en, b1_en, bfu, cesb, de, gate_b, bfdu, cdgb, gateo);
  hipLaunchKernelGGL(fade_kern,   dim3(800),  dim3(512), 0, stream,
                     wc, cesb, cdgb, conv2_b, kernb);
  hipLaunchKernelGGL(fade_final,  dim3(3200), dim3(256), 0, stream,
                     en, de, kernb, gateo, out);
}